// Round 1
// baseline (504.054 us; speedup 1.0000x reference)
//
#include <hip/hip_runtime.h>
#include <hip/hip_bf16.h>

// Problem constants (B=2, L=1024, D=256, C=16, DEPTH=4)
constexpr int Bb   = 2;
constexpr int Ll   = 1024;
constexpr int Dd   = 256;
constexpr int Cc   = 16;
constexpr int Nn   = 64;              // chunks per sequence
constexpr int TOKn = Bb * Ll;         // 2048 tokens
constexpr int NCn  = Bb * Nn;         // 128 chunks total
constexpr int DDn  = Dd * Dd;         // 65536
constexpr int PPn  = 4 * DDn;         // 262144 packed update elems per chunk
constexpr float EPSf = 1.1920929e-07f;

__device__ __forceinline__ float sigm(float x){ return 1.0f/(1.0f + expf(-x)); }
__device__ __forceinline__ float silu_(float x){ return x * sigm(x); }
__device__ __forceinline__ float dsilu_(float x){ float s = sigm(x); return s*(1.0f + x*(1.0f - s)); }

// 256-thread block sum (4 waves)
__device__ __forceinline__ float block_sum(float v, float* red){
    #pragma unroll
    for (int off = 32; off; off >>= 1) v += __shfl_down(v, off, 64);
    if ((threadIdx.x & 63) == 0) red[threadIdx.x >> 6] = v;
    __syncthreads();
    float r = red[0] + red[1] + red[2] + red[3];
    __syncthreads();
    return r;
}

__device__ __forceinline__ void fma16(float acc[16], const float4* xp, float w){
    #pragma unroll
    for (int q = 0; q < 4; ++q){
        float4 x = xp[q];
        acc[4*q+0] += x.x*w; acc[4*q+1] += x.y*w;
        acc[4*q+2] += x.z*w; acc[4*q+3] += x.w*w;
    }
}

__device__ __forceinline__ float dot16(const float4* ap, const float gr[16]){
    float s = 0.0f;
    #pragma unroll
    for (int q = 0; q < 4; ++q){
        float4 a = ap[q];
        s += a.x*gr[4*q+0] + a.y*gr[4*q+1] + a.z*gr[4*q+2] + a.w*gr[4*q+3];
    }
    return s;
}

// acc[c] = sum_k X[k][c] * W[k*Dd + d]   (X = transposed [k][c] LDS tile; W col d)
__device__ __forceinline__ void mm16(const float (*__restrict__ X)[16],
                                     const float* __restrict__ W,
                                     int d, float acc[16]){
    #pragma unroll
    for (int c = 0; c < 16; ++c) acc[c] = 0.0f;
    for (int k = 0; k < Dd; ++k){
        float w = W[k*Dd + d];
        fma16(acc, (const float4*)X[k], w);
    }
}

// out[r][d] = sum_c A[r][c] * gr[c]   (weight-grad outer product, coalesced store)
__device__ __forceinline__ void wgrad16(const float (*__restrict__ A)[16],
                                        const float gr[16],
                                        float* __restrict__ outp, int d){
    for (int r = 0; r < Dd; ++r){
        outp[(size_t)r*Dd + d] = dot16((const float4*)A[r], gr);
    }
}

// ---- K0a: store rmsnorm + shifted retrieve rmsnorm ----
__global__ __launch_bounds__(256) void knorm(const float* __restrict__ seq,
        const float* __restrict__ wsn, const float* __restrict__ wrn,
        float* __restrict__ sn, float* __restrict__ rn){
    __shared__ float red[4];
    int t = blockIdx.x;            // global token 0..2047 (block-uniform)
    int b = t >> 10, tl = t & 1023;
    int d = threadIdx.x;
    float x = seq[(size_t)t*Dd + d];
    float ss = block_sum(x*x, red);
    float r = rsqrtf(ss*(1.0f/Dd) + EPSf);
    sn[(size_t)t*Dd + d] = x*r*wsn[d];
    // rn[t] = rmsnorm(seq[b, tl+15]) for tl<=1008 else 0 (shift + pad)
    float y = 0.0f;
    if (tl <= Ll - Cc){            // block-uniform condition -> barriers safe
        float xv = seq[((size_t)b*Ll + tl + (Cc-1))*Dd + d];
        float s2 = block_sum(xv*xv, red);
        float r2 = rsqrtf(s2*(1.0f/Dd) + EPSf);
        y = xv*r2*wrn[d];
    }
    rn[(size_t)t*Dd + d] = y;
}

// ---- K0b: chunk means -> sigmoid gates ----
__global__ __launch_bounds__(256) void kgates(const float* __restrict__ sn,
        const float* __restrict__ wa, const float* __restrict__ wm,
        const float* __restrict__ wd, float* __restrict__ lrg,
        float* __restrict__ momg, float* __restrict__ decg){
    __shared__ float red[4];
    int g = blockIdx.x, d = threadIdx.x;   // chunk 0..127
    float a = 0.0f;
    #pragma unroll
    for (int c = 0; c < 16; ++c) a += sn[((size_t)g*16 + c)*Dd + d];
    float cm = a * (1.0f/16.0f);
    float da = block_sum(cm*wa[d], red);
    float dm = block_sum(cm*wm[d], red);
    float dc = block_sum(cm*wd[d], red);
    if (d == 0){
        lrg[g]  = sigm(da);
        momg[g] = sigm(dm);
        decg[g] = sigm(dc);
    }
}

// ---- transpose W1,W2,W3 for coalesced dgrad ----
__global__ __launch_bounds__(256) void ktransp(const float* __restrict__ S1,
        const float* __restrict__ S2, const float* __restrict__ S3,
        float* __restrict__ T1, float* __restrict__ T2, float* __restrict__ T3){
    int j = blockIdx.x, d = threadIdx.x, m = blockIdx.y;
    const float* S = (m==0)?S1:(m==1)?S2:S3;
    float* T = (m==0)?T1:(m==1)?T2:T3;
    T[(size_t)j*Dd + d] = S[(size_t)d*Dd + j];
}

// ---- generic [16 x 256] @ [256 x ncols] GEMM (kv and q) ----
__global__ __launch_bounds__(256) void kgemm(const float* __restrict__ in,
        const float* __restrict__ W, float* __restrict__ out, int ncols){
    __shared__ float AT[Dd][16];
    int rb = blockIdx.x, cb = blockIdx.y, tid = threadIdx.x;
    #pragma unroll
    for (int c = 0; c < 16; ++c) AT[tid][c] = in[((size_t)rb*16 + c)*Dd + tid];
    __syncthreads();
    int col = cb*256 + tid;
    float acc[16];
    #pragma unroll
    for (int c = 0; c < 16; ++c) acc[c] = 0.0f;
    for (int k = 0; k < Dd; ++k){
        float w = W[(size_t)k*ncols + col];
        fma16(acc, (const float4*)AT[k], w);
    }
    #pragma unroll
    for (int c = 0; c < 16; ++c) out[((size_t)rb*16 + c)*ncols + col] = acc[c];
}

// ---- K2: per-chunk MLP fwd + backward at base weights -> surprise (= -lr * grad) ----
// 4 ping-pong LDS buffers [256][16] = 64KB total.
__global__ __launch_bounds__(256) void kgrads(const float* __restrict__ kvb,
        const float* __restrict__ W0, const float* __restrict__ W1,
        const float* __restrict__ W2, const float* __restrict__ W3,
        const float* __restrict__ W1T, const float* __restrict__ W2T,
        const float* __restrict__ W3T, const float* __restrict__ lrg,
        float* __restrict__ sup){
    __shared__ float B0[Dd][16], B1[Dd][16], B2[Dd][16], B3[Dd][16];
    int g = blockIdx.x, d = threadIdx.x;
    size_t tb = (size_t)g * Cc;
    #pragma unroll
    for (int c = 0; c < 16; ++c) B0[d][c] = kvb[(tb + c)*(2*Dd) + d];   // keys
    __syncthreads();

    float h1[16], h2[16], h3[16], acc[16], gr[16];

    mm16(B0, W0, d, acc);                       // h1 = K@W0 (col d)
    #pragma unroll
    for (int c = 0; c < 16; ++c){ h1[c] = acc[c]; B1[d][c] = silu_(acc[c]); }
    __syncthreads();
    mm16(B1, W1, d, acc);                       // h2
    #pragma unroll
    for (int c = 0; c < 16; ++c){ h2[c] = acc[c]; B2[d][c] = silu_(acc[c]); }
    __syncthreads();
    mm16(B2, W2, d, acc);                       // h3
    #pragma unroll
    for (int c = 0; c < 16; ++c){ h3[c] = acc[c]; B3[d][c] = silu_(acc[c]); }
    __syncthreads();
    mm16(B3, W3, d, acc);                       // pred
    float sc = -2.0f * lrg[g] * (1.0f/Dd);      // fold -lr * dL/dpred scale
    #pragma unroll
    for (int c = 0; c < 16; ++c){
        gr[c] = sc * (acc[c] - kvb[(tb + c)*(2*Dd) + Dd + d]);   // g4 col d
        B0[d][c] = gr[c];                       // K dead (reloaded later)
    }
    __syncthreads();
    float* supg = sup + (size_t)g * PPn;
    wgrad16(B3, gr, supg + 3*(size_t)DDn, d);   // sW3 = a3^T g4
    mm16(B0, W3T, d, acc);                      // g4 @ W3^T
    #pragma unroll
    for (int c = 0; c < 16; ++c) gr[c] = acc[c] * dsilu_(h3[c]);   // g3
    __syncthreads();                            // all done reading B3 (a3)
    #pragma unroll
    for (int c = 0; c < 16; ++c) B3[d][c] = gr[c];
    __syncthreads();
    wgrad16(B2, gr, supg + 2*(size_t)DDn, d);   // sW2 = a2^T g3
    mm16(B3, W2T, d, acc);                      // g3 @ W2^T
    #pragma unroll
    for (int c = 0; c < 16; ++c) gr[c] = acc[c] * dsilu_(h2[c]);   // g2
    __syncthreads();                            // all done reading B2 (a2)
    #pragma unroll
    for (int c = 0; c < 16; ++c) B2[d][c] = gr[c];
    __syncthreads();
    wgrad16(B1, gr, supg + 1*(size_t)DDn, d);   // sW1 = a1^T g2
    mm16(B2, W1T, d, acc);                      // g2 @ W1^T
    #pragma unroll
    for (int c = 0; c < 16; ++c) gr[c] = acc[c] * dsilu_(h1[c]);   // g1 (regs only)
    __syncthreads();                            // all done reading B0 (g4)
    #pragma unroll
    for (int c = 0; c < 16; ++c) B0[d][c] = kvb[(tb + c)*(2*Dd) + d];  // reload keys
    __syncthreads();
    wgrad16(B0, gr, supg, d);                   // sW0 = K^T g1
}

// ---- K3: fused momentum + decay scans, in place on the surprise buffer ----
__global__ __launch_bounds__(256) void kscan(float* __restrict__ sup,
        const float* __restrict__ momg, const float* __restrict__ decg){
    int p = blockIdx.x*256 + threadIdx.x;   // 0..PPn-1
    int b = blockIdx.y;
    float ms = 0.0f, us = 0.0f;
    for (int n = 0; n < Nn; ++n){
        int gg = b*Nn + n;
        size_t idx = (size_t)gg*PPn + p;
        float s = sup[idx];
        ms = momg[gg]*ms + s;               // momentum_t = mom_t * m_{t-1} + surprise_t
        us = (1.0f - decg[gg])*us + ms;     // updates_t  = (1-decay_t) * u_{t-1} + m_t
        sup[idx] = us;                      // in place: each addr owned by one thread
    }
}

// ---- K4: fast-weight retrieval MLP + post rmsnorm + output shift ----
__global__ __launch_bounds__(256) void kretr(const float* __restrict__ qb,
        const float* __restrict__ W0, const float* __restrict__ W1,
        const float* __restrict__ W2, const float* __restrict__ W3,
        const float* __restrict__ upd, const float* __restrict__ wpost,
        float* __restrict__ out){
    __shared__ float XT[Dd][16];
    __shared__ float red[4];
    int g = blockIdx.x, d = threadIdx.x;
    int b = g >> 6, n = g & 63;
    size_t tb = (size_t)g * Cc;
    #pragma unroll
    for (int c = 0; c < 16; ++c) XT[d][c] = qb[(tb + c)*Dd + d];
    __syncthreads();
    float acc[16];
    const float* updg = upd + (size_t)g * PPn;
    for (int layer = 0; layer < 4; ++layer){
        const float* Wp = (layer==0)?W0:(layer==1)?W1:(layer==2)?W2:W3;
        const float* Up = updg + (size_t)layer*DDn;
        #pragma unroll
        for (int c = 0; c < 16; ++c) acc[c] = 0.0f;
        for (int k = 0; k < Dd; ++k){
            float w = Wp[(size_t)k*Dd + d] + Up[(size_t)k*Dd + d];  // fast weight
            fma16(acc, (const float4*)XT[k], w);
        }
        if (layer < 3){
            __syncthreads();
            #pragma unroll
            for (int c = 0; c < 16; ++c) XT[d][c] = silu_(acc[c]);
            __syncthreads();
        }
    }
    float wpd = wpost[d];
    for (int c = 0; c < 16; ++c){
        float ss = block_sum(acc[c]*acc[c], red);
        float r = rsqrtf(ss*(1.0f/Dd) + EPSf);
        int tp = n*16 + c + (Cc-1);          // output shift by C-1
        if (tp < Ll) out[((size_t)b*Ll + tp)*Dd + d] = acc[c]*r*wpd;
    }
    if (n == 0){                             // zero rows 0..14 (d_out is poisoned)
        #pragma unroll
        for (int t = 0; t < Cc-1; ++t) out[((size_t)b*Ll + t)*Dd + d] = 0.0f;
    }
}

extern "C" void kernel_launch(void* const* d_in, const int* in_sizes, int n_in,
                              void* d_out, int out_size, void* d_ws, size_t ws_size,
                              hipStream_t stream) {
    const float* seq     = (const float*)d_in[0];
    const float* w_store = (const float*)d_in[1];
    const float* w_retr  = (const float*)d_in[2];
    const float* w_post  = (const float*)d_in[3];
    const float* Wq      = (const float*)d_in[4];
    const float* Wkv     = (const float*)d_in[5];
    const float* w_adapt = (const float*)d_in[6];
    const float* w_mom   = (const float*)d_in[7];
    const float* w_decay = (const float*)d_in[8];
    const float* W0      = (const float*)d_in[9];
    const float* W1      = (const float*)d_in[10];
    const float* W2      = (const float*)d_in[11];
    const float* W3      = (const float*)d_in[12];

    // workspace layout (fp32): ~146 MB total
    float* ws   = (float*)d_ws;
    float* sn   = ws;                          // 2048*256
    float* rn   = sn   + (size_t)TOKn*Dd;      // 2048*256
    float* kvb  = rn   + (size_t)TOKn*Dd;      // 2048*512
    float* qb   = kvb  + (size_t)TOKn*2*Dd;    // 2048*256
    float* lrg  = qb   + (size_t)TOKn*Dd;      // 128
    float* momg = lrg  + NCn;                  // 128
    float* decg = momg + NCn;                  // 128
    float* W1T  = decg + NCn;                  // 65536
    float* W2T  = W1T  + DDn;
    float* W3T  = W2T  + DDn;
    float* sup  = W3T  + DDn;                  // 128*262144 (surprise -> updates in place)

    knorm <<<dim3(TOKn),    256, 0, stream>>>(seq, w_store, w_retr, sn, rn);
    kgates<<<dim3(NCn),     256, 0, stream>>>(sn, w_adapt, w_mom, w_decay, lrg, momg, decg);
    ktransp<<<dim3(Dd, 3),  256, 0, stream>>>(W1, W2, W3, W1T, W2T, W3T);
    kgemm <<<dim3(TOKn/16, 2), 256, 0, stream>>>(sn, Wkv, kvb, 2*Dd);
    kgemm <<<dim3(TOKn/16, 1), 256, 0, stream>>>(rn, Wq, qb, Dd);
    kgrads<<<dim3(NCn),     256, 0, stream>>>(kvb, W0, W1, W2, W3, W1T, W2T, W3T, lrg, sup);
    kscan <<<dim3(PPn/256, Bb), 256, 0, stream>>>(sup, momg, decg);
    kretr <<<dim3(NCn),     256, 0, stream>>>(qb, W0, W1, W2, W3, sup, w_post, (float*)d_out);
}

// Round 2
// 483.645 us; speedup vs baseline: 1.0422x; 1.0422x over previous
//
#include <hip/hip_runtime.h>
#include <hip/hip_bf16.h>

// B=2, L=1024, D=256, C=16, DEPTH=4
constexpr int Dd   = 256;
constexpr int Nn   = 64;              // chunks per sequence
constexpr int NCn  = 128;             // total chunks
constexpr int TOKn = 2048;
constexpr int DDn  = 65536;           // D*D
constexpr int PPn  = 4 * DDn;         // 262144 packed update elems per chunk
constexpr float EPSf = 1.1920929e-07f;

__device__ __forceinline__ float sigm(float x){ return 1.0f/(1.0f + expf(-x)); }
__device__ __forceinline__ float silu_(float x){ return x * sigm(x); }
__device__ __forceinline__ float dsilu_(float x){ float s = sigm(x); return s*(1.0f + x*(1.0f - s)); }

__device__ __forceinline__ unsigned short f2bu(float x){
    __hip_bfloat16 b = __float2bfloat16(x);
    unsigned short u; __builtin_memcpy(&u, &b, 2); return u;
}
__device__ __forceinline__ float bu2f(unsigned short u){
    __hip_bfloat16 b; __builtin_memcpy(&b, &u, 2); return __bfloat162float(b);
}

// 256-thread block sum (4 waves)
__device__ __forceinline__ float block_sum(float v, float* red){
    #pragma unroll
    for (int off = 32; off; off >>= 1) v += __shfl_down(v, off, 64);
    if ((threadIdx.x & 63) == 0) red[threadIdx.x >> 6] = v;
    __syncthreads();
    float r = red[0] + red[1] + red[2] + red[3];
    __syncthreads();
    return r;
}

// ---- fused per-chunk norms + gates (128 blocks) ----
__global__ __launch_bounds__(256) void kchunk(const float* __restrict__ seq,
        const float* __restrict__ wsn, const float* __restrict__ wrn,
        const float* __restrict__ wa, const float* __restrict__ wm,
        const float* __restrict__ wdk,
        float* __restrict__ snT, float* __restrict__ rnT,
        float* __restrict__ lrg, float* __restrict__ momg, float* __restrict__ decg){
    __shared__ float red[4];
    int g = blockIdx.x, d = threadIdx.x, nl = g & 63;
    float wsd = wsn[d], wrd = wrn[d];
    float sv[16], rv[16];
    float cms = 0.f;
    #pragma unroll
    for (int c = 0; c < 16; ++c){
        float x = seq[((size_t)g*16 + c)*Dd + d];
        float ss = block_sum(x*x, red);
        float v = x * rsqrtf(ss*(1.f/Dd) + EPSf) * wsd;
        sv[c] = v; cms += v;
    }
    #pragma unroll
    for (int c = 0; c < 16; ++c){
        float x = (nl*16 + c <= 1008) ? seq[((size_t)g*16 + c + 15)*Dd + d] : 0.f;
        float ss = block_sum(x*x, red);
        rv[c] = x * rsqrtf(ss*(1.f/Dd) + EPSf) * wrd;
    }
    float4* sp = (float4*)&snT[((size_t)g*Dd + d)*16];
    sp[0] = make_float4(sv[0], sv[1], sv[2], sv[3]);
    sp[1] = make_float4(sv[4], sv[5], sv[6], sv[7]);
    sp[2] = make_float4(sv[8], sv[9], sv[10], sv[11]);
    sp[3] = make_float4(sv[12], sv[13], sv[14], sv[15]);
    float4* rp = (float4*)&rnT[((size_t)g*Dd + d)*16];
    rp[0] = make_float4(rv[0], rv[1], rv[2], rv[3]);
    rp[1] = make_float4(rv[4], rv[5], rv[6], rv[7]);
    rp[2] = make_float4(rv[8], rv[9], rv[10], rv[11]);
    rp[3] = make_float4(rv[12], rv[13], rv[14], rv[15]);
    float cm = cms * (1.f/16.f);
    float da = block_sum(cm*wa[d], red);
    float dm = block_sum(cm*wm[d], red);
    float dc2 = block_sum(cm*wdk[d], red);
    if (d == 0){ lrg[g] = sigm(da); momg[g] = sigm(dm); decg[g] = sigm(dc2); }
}

// ---- transpose W1,W2,W3 ----
__global__ __launch_bounds__(256) void ktransp(const float* __restrict__ S1,
        const float* __restrict__ S2, const float* __restrict__ S3,
        float* __restrict__ T1, float* __restrict__ T2, float* __restrict__ T3){
    int j = blockIdx.x, d = threadIdx.x, m = blockIdx.y;
    const float* S = (m==0)?S1:(m==1)?S2:S3;
    float* T = (m==0)?T1:(m==1)?T2:T3;
    T[(size_t)j*Dd + d] = S[(size_t)d*Dd + j];
}

// ---- generic chunk GEMM: out[g][c][d] = act( sum_k AT[g][k][c] * (B[k][d] (+U)) ) ----
// modes: 0 kv (slices<4: K normal + KT; else V normal)
//        1 q (T only)   2 fwd (h normal, silu normal, siluT)
//        3 fwdlast (G4 = -lr*2/D*(pred-V): normal+T)
//        4 bwd (acc*dsilu(H): normal+T)   5 bwdlast (normal only)
//        6 retr (W+U, siluT only)         7 retrlast (W+U, normal only)
__global__ __launch_bounds__(256) void kmm(const float* __restrict__ AT,
        const float* __restrict__ Bw, int bstride,
        const unsigned short* __restrict__ U,
        const float* __restrict__ Hpre, const float* __restrict__ Vv,
        const float* __restrict__ lrg,
        float* __restrict__ out_n, float* __restrict__ out_n2,
        float* __restrict__ out_t, int mode){
    int s = blockIdx.x, g = blockIdx.y;
    int dc = threadIdx.x & 63, cg = threadIdx.x >> 6;
    int d = s*64 + dc;
    const float4* atp = (const float4*)AT + (size_t)g*1024 + cg;
    float acc[4] = {0.f, 0.f, 0.f, 0.f};
    if (mode >= 6){
        const unsigned short* Up = U + (size_t)g*PPn;
        #pragma unroll 4
        for (int k = 0; k < Dd; ++k){
            float4 xa = atp[(size_t)k*4];
            float w = Bw[(size_t)k*bstride + d] + bu2f(Up[(size_t)k*Dd + d]);
            acc[0] += xa.x*w; acc[1] += xa.y*w; acc[2] += xa.z*w; acc[3] += xa.w*w;
        }
    } else {
        #pragma unroll 4
        for (int k = 0; k < Dd; ++k){
            float4 xa = atp[(size_t)k*4];
            float w = Bw[(size_t)k*bstride + d];
            acc[0] += xa.x*w; acc[1] += xa.y*w; acc[2] += xa.z*w; acc[3] += xa.w*w;
        }
    }
    size_t rb = ((size_t)g*16 + cg*4)*Dd + d;          // normal-layout base (row stride Dd)
    size_t tb = ((size_t)g*Dd + d)*16 + cg*4;          // T-layout base
    switch (mode){
    case 0: {
        if (s < 4){
            #pragma unroll
            for (int j = 0; j < 4; ++j) out_n[rb + (size_t)j*Dd] = acc[j];
            *(float4*)&out_t[tb] = make_float4(acc[0], acc[1], acc[2], acc[3]);
        } else {
            size_t vb = ((size_t)g*16 + cg*4)*Dd + (d - 256);
            #pragma unroll
            for (int j = 0; j < 4; ++j) out_n2[vb + (size_t)j*Dd] = acc[j];
        }
    } break;
    case 1: {
        *(float4*)&out_t[tb] = make_float4(acc[0], acc[1], acc[2], acc[3]);
    } break;
    case 2: {
        float sl[4];
        #pragma unroll
        for (int j = 0; j < 4; ++j){
            out_n[rb + (size_t)j*Dd] = acc[j];
            sl[j] = silu_(acc[j]);
            out_n2[rb + (size_t)j*Dd] = sl[j];
        }
        *(float4*)&out_t[tb] = make_float4(sl[0], sl[1], sl[2], sl[3]);
    } break;
    case 3: {
        float sc = -lrg[g] * (2.0f/Dd);
        float gv[4];
        #pragma unroll
        for (int j = 0; j < 4; ++j){
            gv[j] = sc * (acc[j] - Vv[rb + (size_t)j*Dd]);
            out_n[rb + (size_t)j*Dd] = gv[j];
        }
        *(float4*)&out_t[tb] = make_float4(gv[0], gv[1], gv[2], gv[3]);
    } break;
    case 4: case 5: {
        float gv[4];
        #pragma unroll
        for (int j = 0; j < 4; ++j){
            gv[j] = acc[j] * dsilu_(Hpre[rb + (size_t)j*Dd]);
            out_n[rb + (size_t)j*Dd] = gv[j];
        }
        if (mode == 4) *(float4*)&out_t[tb] = make_float4(gv[0], gv[1], gv[2], gv[3]);
    } break;
    case 6: {
        *(float4*)&out_t[tb] = make_float4(silu_(acc[0]), silu_(acc[1]), silu_(acc[2]), silu_(acc[3]));
    } break;
    case 7: {
        #pragma unroll
        for (int j = 0; j < 4; ++j) out_n[rb + (size_t)j*Dd] = acc[j];
    } break;
    }
}

// ---- rank-16 outer products -> surprise (bf16), grid (16 subtiles, 128 chunks, 4 layers) ----
__global__ __launch_bounds__(256) void kouter(const float* __restrict__ Kn,
        const float* __restrict__ a1, const float* __restrict__ a2,
        const float* __restrict__ a3, const float* __restrict__ G1,
        const float* __restrict__ G2, const float* __restrict__ G3,
        const float* __restrict__ G4, unsigned short* __restrict__ supb){
    __shared__ float Asub[16][64], Gsub[16][64];
    int st = blockIdx.x, g = blockIdx.y, l = blockIdx.z;
    int r0 = (st >> 2)*64, d0 = (st & 3)*64;
    const float* Ap = (l==0)?Kn:(l==1)?a1:(l==2)?a2:a3;
    const float* Gp = (l==0)?G1:(l==1)?G2:(l==2)?G3:G4;
    int t = threadIdx.x;
    int cs = t >> 4, rl = (t & 15)*4;
    *(float4*)&Asub[cs][rl] = *(const float4*)&Ap[((size_t)g*16 + cs)*Dd + r0 + rl];
    *(float4*)&Gsub[cs][rl] = *(const float4*)&Gp[((size_t)g*16 + cs)*Dd + d0 + rl];
    __syncthreads();
    int ri = t >> 4, di = t & 15;
    float acc[4][4] = {};
    #pragma unroll
    for (int c = 0; c < 16; ++c){
        float4 av = *(const float4*)&Asub[c][ri*4];
        float4 gv = *(const float4*)&Gsub[c][di*4];
        float a4[4] = {av.x, av.y, av.z, av.w};
        float g4[4] = {gv.x, gv.y, gv.z, gv.w};
        #pragma unroll
        for (int i = 0; i < 4; ++i)
            #pragma unroll
            for (int j = 0; j < 4; ++j)
                acc[i][j] += a4[i]*g4[j];
    }
    unsigned short* outp = supb + ((size_t)g*4 + l)*DDn;
    #pragma unroll
    for (int i = 0; i < 4; ++i){
        int r = r0 + ri*4 + i;
        ushort4 u;
        u.x = f2bu(acc[i][0]); u.y = f2bu(acc[i][1]);
        u.z = f2bu(acc[i][2]); u.w = f2bu(acc[i][3]);
        *(ushort4*)(outp + (size_t)r*Dd + d0 + di*4) = u;
    }
}

// ---- fused momentum+decay scans, in place on bf16 surprise buffer ----
__global__ __launch_bounds__(256) void kscan(unsigned short* __restrict__ supb,
        const float* __restrict__ momg, const float* __restrict__ decg){
    int p = blockIdx.x*256 + threadIdx.x;   // 0..PPn-1
    int b = blockIdx.y;
    float ms = 0.f, us = 0.f;
    unsigned short* base = supb + (size_t)b*Nn*PPn + p;
    for (int n = 0; n < Nn; ++n){
        int gg = b*Nn + n;
        unsigned short* ptr = base + (size_t)n*PPn;
        float s = bu2f(*ptr);
        ms = momg[gg]*ms + s;
        us = (1.f - decg[gg])*us + ms;
        *ptr = f2bu(us);
    }
}

// ---- post rmsnorm + output shift (2048 blocks) ----
__global__ __launch_bounds__(256) void knormout(const float* __restrict__ y3,
        const float* __restrict__ wpost, float* __restrict__ out){
    __shared__ float red[4];
    int tt = blockIdx.x, d = threadIdx.x;
    int g = tt >> 4, c = tt & 15, b = g >> 6, n = g & 63;
    float y = y3[(size_t)tt*Dd + d];
    float ss = block_sum(y*y, red);
    float val = y * rsqrtf(ss*(1.f/Dd) + EPSf) * wpost[d];
    int tp = n*16 + c + 15;
    if (tp < 1024) out[((size_t)b*1024 + tp)*Dd + d] = val;
    if (n == 0 && c == 0){
        #pragma unroll
        for (int t2 = 0; t2 < 15; ++t2) out[((size_t)b*1024 + t2)*Dd + d] = 0.f;
    }
}

extern "C" void kernel_launch(void* const* d_in, const int* in_sizes, int n_in,
                              void* d_out, int out_size, void* d_ws, size_t ws_size,
                              hipStream_t stream) {
    const float* seq     = (const float*)d_in[0];
    const float* w_store = (const float*)d_in[1];
    const float* w_retr  = (const float*)d_in[2];
    const float* w_post  = (const float*)d_in[3];
    const float* Wq      = (const float*)d_in[4];
    const float* Wkv     = (const float*)d_in[5];
    const float* w_adapt = (const float*)d_in[6];
    const float* w_mom   = (const float*)d_in[7];
    const float* w_decay = (const float*)d_in[8];
    const float* W0      = (const float*)d_in[9];
    const float* W1      = (const float*)d_in[10];
    const float* W2      = (const float*)d_in[11];
    const float* W3      = (const float*)d_in[12];

    // workspace layout (floats): 22 tiles of 524288 + WTs + gates + bf16 sup = ~114 MB
    const size_t T = (size_t)NCn * Dd * 16;   // 524288
    float* ws  = (float*)d_ws;
    float* snT = ws;          float* rnT = ws + 1*T;  float* KT  = ws + 2*T;
    float* Kn  = ws + 3*T;    float* Vn  = ws + 4*T;  float* qT  = ws + 5*T;
    float* a1T = ws + 6*T;    float* a2T = ws + 7*T;  float* a3T = ws + 8*T;
    float* a1n = ws + 9*T;    float* a2n = ws + 10*T; float* a3n = ws + 11*T;
    float* h1  = ws + 12*T;   float* h2  = ws + 13*T; float* h3  = ws + 14*T;
    float* G1  = ws + 15*T;   float* G2  = ws + 16*T; float* G3  = ws + 17*T;
    float* G4  = ws + 18*T;
    float* G4T = ws + 19*T;   float* G3T = ws + 20*T; float* G2T = ws + 21*T;
    float* W1T = ws + 22*T;
    float* W2T = W1T + DDn;   float* W3T = W2T + DDn;
    float* lrg  = W3T + DDn;  float* momg = lrg + NCn; float* decg = momg + NCn;
    unsigned short* supb = (unsigned short*)(decg + NCn);   // 33.5M bf16 = 67MB
    float* y3 = Kn;           // Kn dead after kouter

    kchunk<<<dim3(NCn), 256, 0, stream>>>(seq, w_store, w_retr, w_adapt, w_mom,
                                          w_decay, snT, rnT, lrg, momg, decg);
    ktransp<<<dim3(Dd, 3), 256, 0, stream>>>(W1, W2, W3, W1T, W2T, W3T);
    // projections
    kmm<<<dim3(8, NCn), 256, 0, stream>>>(snT, Wkv, 512, nullptr, nullptr, nullptr,
                                          nullptr, Kn, Vn, KT, 0);
    kmm<<<dim3(4, NCn), 256, 0, stream>>>(rnT, Wq, 256, nullptr, nullptr, nullptr,
                                          nullptr, nullptr, nullptr, qT, 1);
    // forward MLP at base weights
    kmm<<<dim3(4, NCn), 256, 0, stream>>>(KT,  W0, 256, nullptr, nullptr, nullptr,
                                          nullptr, h1, a1n, a1T, 2);
    kmm<<<dim3(4, NCn), 256, 0, stream>>>(a1T, W1, 256, nullptr, nullptr, nullptr,
                                          nullptr, h2, a2n, a2T, 2);
    kmm<<<dim3(4, NCn), 256, 0, stream>>>(a2T, W2, 256, nullptr, nullptr, nullptr,
                                          nullptr, h3, a3n, a3T, 2);
    kmm<<<dim3(4, NCn), 256, 0, stream>>>(a3T, W3, 256, nullptr, nullptr, Vn,
                                          lrg, G4, nullptr, G4T, 3);
    // backward dgrads
    kmm<<<dim3(4, NCn), 256, 0, stream>>>(G4T, W3T, 256, nullptr, h3, nullptr,
                                          nullptr, G3, nullptr, G3T, 4);
    kmm<<<dim3(4, NCn), 256, 0, stream>>>(G3T, W2T, 256, nullptr, h2, nullptr,
                                          nullptr, G2, nullptr, G2T, 4);
    kmm<<<dim3(4, NCn), 256, 0, stream>>>(G2T, W1T, 256, nullptr, h1, nullptr,
                                          nullptr, G1, nullptr, nullptr, 5);
    // surprise outer products + scans
    kouter<<<dim3(16, NCn, 4), 256, 0, stream>>>(Kn, a1n, a2n, a3n, G1, G2, G3, G4, supb);
    kscan<<<dim3(PPn/256, 2), 256, 0, stream>>>(supb, momg, decg);
    // retrieval with fast weights (ping-pong xT through snT/rnT, both dead)
    kmm<<<dim3(4, NCn), 256, 0, stream>>>(qT,  W0, 256, supb + 0*DDn, nullptr, nullptr,
                                          nullptr, nullptr, nullptr, snT, 6);
    kmm<<<dim3(4, NCn), 256, 0, stream>>>(snT, W1, 256, supb + 1*DDn, nullptr, nullptr,
                                          nullptr, nullptr, nullptr, rnT, 6);
    kmm<<<dim3(4, NCn), 256, 0, stream>>>(rnT, W2, 256, supb + 2*DDn, nullptr, nullptr,
                                          nullptr, nullptr, nullptr, snT, 6);
    kmm<<<dim3(4, NCn), 256, 0, stream>>>(snT, W3, 256, supb + 3*DDn, nullptr, nullptr,
                                          nullptr, y3, nullptr, nullptr, 7);
    knormout<<<dim3(TOKn), 256, 0, stream>>>(y3, w_post, (float*)d_out);
}

// Round 3
// 214.277 us; speedup vs baseline: 2.3524x; 2.2571x over previous
//
#include <hip/hip_runtime.h>
#include <hip/hip_bf16.h>

typedef __attribute__((ext_vector_type(8)))  short s8v;   // 8 bf16 (4 VGPR)
typedef __attribute__((ext_vector_type(4)))  float f4v;   // 16x16 C/D
typedef __attribute__((ext_vector_type(16))) float f16v;  // 32x32 C/D

constexpr int Dd   = 256;
constexpr int Nn   = 64;
constexpr int NCn  = 128;
constexpr int DDn  = 65536;
constexpr int PPn  = 262144;          // 4*D*D per chunk
constexpr int XP   = 264;             // padded LDS row (bf16 elems): 528B, 16B-aligned
constexpr float EPSf = 1.1920929e-07f;

__device__ __forceinline__ float sigm(float x){ return 1.0f/(1.0f + expf(-x)); }
__device__ __forceinline__ float silu_(float x){ return x * sigm(x); }
__device__ __forceinline__ float dsilu_(float x){ float s = sigm(x); return s*(1.0f + x*(1.0f - s)); }

__device__ __forceinline__ unsigned short f2b(float x){
    __hip_bfloat16 b = __float2bfloat16(x);
    unsigned short u; __builtin_memcpy(&u, &b, 2); return u;
}
__device__ __forceinline__ float b2f(unsigned short u){
    __hip_bfloat16 b; __builtin_memcpy(&b, &u, 2); return __bfloat162float(b);
}

__device__ __forceinline__ float block_sum(float v, float* red){
    #pragma unroll
    for (int off = 32; off; off >>= 1) v += __shfl_down(v, off, 64);
    if ((threadIdx.x & 63) == 0) red[threadIdx.x >> 6] = v;
    __syncthreads();
    float r = red[0] + red[1] + red[2] + red[3];
    __syncthreads();
    return r;
}

// ---- weights -> bf16, both layouts ----
// m 0..3: WTb[m]=W_m^T ; m 4..6: Wb[m-4]=W_{m-3} row-major ; m 7: WqT ; m 8,9: WkvT
__global__ __launch_bounds__(256) void kwcast(const float* __restrict__ Wq,
        const float* __restrict__ Wkv, const float* __restrict__ W0,
        const float* __restrict__ W1, const float* __restrict__ W2,
        const float* __restrict__ W3, unsigned short* __restrict__ WTb,
        unsigned short* __restrict__ Wb, unsigned short* __restrict__ WqTb,
        unsigned short* __restrict__ WkvTb){
    int j = blockIdx.x, m = blockIdx.y, k = threadIdx.x;
    if (m < 4){
        const float* W = (m==0)?W0:(m==1)?W1:(m==2)?W2:W3;
        WTb[(size_t)m*DDn + j*256 + k] = f2b(W[(size_t)k*256 + j]);
    } else if (m < 7){
        const float* W = (m==4)?W1:(m==5)?W2:W3;
        Wb[(size_t)(m-4)*DDn + j*256 + k] = f2b(W[(size_t)j*256 + k]);
    } else if (m == 7){
        WqTb[(size_t)j*256 + k] = f2b(Wq[(size_t)k*256 + j]);
    } else {
        int r = j + (m-8)*256;
        WkvTb[(size_t)r*256 + k] = f2b(Wkv[(size_t)k*512 + r]);
    }
}

// ---- norms + gates; bf16 chunk activations row-major [g][c][d] ----
__global__ __launch_bounds__(256) void kprep(const float* __restrict__ seq,
        const float* __restrict__ wsn, const float* __restrict__ wrn,
        const float* __restrict__ wa, const float* __restrict__ wm,
        const float* __restrict__ wdk, unsigned short* __restrict__ snb,
        unsigned short* __restrict__ rnb, float* __restrict__ lrg,
        float* __restrict__ momg, float* __restrict__ decg){
    __shared__ float red[4];
    int g = blockIdx.x, d = threadIdx.x, nl = g & 63;
    float wsd = wsn[d], wrd = wrn[d];
    float cms = 0.f;
    #pragma unroll
    for (int c = 0; c < 16; ++c){
        float x = seq[((size_t)g*16 + c)*Dd + d];
        float ss = block_sum(x*x, red);
        float v = x * rsqrtf(ss*(1.f/Dd) + EPSf) * wsd;
        snb[(size_t)g*4096 + c*256 + d] = f2b(v);
        cms += v;
    }
    #pragma unroll
    for (int c = 0; c < 16; ++c){
        float x = (nl*16 + c <= 1008) ? seq[((size_t)g*16 + c + 15)*Dd + d] : 0.f;
        float ss = block_sum(x*x, red);
        float v = x * rsqrtf(ss*(1.f/Dd) + EPSf) * wrd;
        rnb[(size_t)g*4096 + c*256 + d] = f2b(v);
    }
    float cm = cms * (1.f/16.f);
    float da = block_sum(cm*wa[d], red);
    float dm = block_sum(cm*wm[d], red);
    float dc = block_sum(cm*wdk[d], red);
    if (d == 0){ lrg[g] = sigm(da); momg[g] = sigm(dm); decg[g] = sigm(dc); }
}

// ---- fused store: proj K,V -> MLP fwd -> bwd -> wgrads -> surprise^T (bf16) ----
// grid (2, 128): bh = write-half, g = chunk. 512 threads = 8 waves.
__global__ __launch_bounds__(512, 1) void kstore(const unsigned short* __restrict__ snb,
        const unsigned short* __restrict__ WkvTb, const unsigned short* __restrict__ WTb,
        const unsigned short* __restrict__ Wb, const float* __restrict__ lrg,
        unsigned short* __restrict__ supb){
    __shared__ unsigned short xl[4][16][XP];   // x0=K, x1..x3 activations
    __shared__ unsigned short Gs[16][XP];      // current grad, row-major
    int tid = threadIdx.x, w = tid >> 6, lane = tid & 63;
    int m16 = lane & 15, q16 = lane >> 4;
    int m32 = lane & 31, q32 = lane >> 5;
    int g = blockIdx.y, bh = blockIdx.x;
    float sc = -2.f * lrg[g] * (1.f/256.f);

    // A-frags of key-input sn (global, row m16)
    s8v af[8];
    const unsigned short* arow = snb + (size_t)g*4096 + m16*256 + q16*8;
    #pragma unroll
    for (int i = 0; i < 8; ++i) af[i] = *(const s8v*)(arow + i*32);

    // proj: K tiles -> xl[0]; V tiles stay in regs
    f4v vacc[2];
    #pragma unroll
    for (int t = 0; t < 2; ++t){
        int n0 = w*32 + t*16;
        f4v ka = {0.f,0.f,0.f,0.f}, va = {0.f,0.f,0.f,0.f};
        const unsigned short* brK = WkvTb + (size_t)(n0 + m16)*256 + q16*8;
        const unsigned short* brV = WkvTb + (size_t)(256 + n0 + m16)*256 + q16*8;
        #pragma unroll
        for (int i = 0; i < 8; ++i){
            s8v bK = *(const s8v*)(brK + i*32);
            s8v bV = *(const s8v*)(brV + i*32);
            ka = __builtin_amdgcn_mfma_f32_16x16x32_bf16(af[i], bK, ka, 0, 0, 0);
            va = __builtin_amdgcn_mfma_f32_16x16x32_bf16(af[i], bV, va, 0, 0, 0);
        }
        vacc[t] = va;
        #pragma unroll
        for (int r = 0; r < 4; ++r) xl[0][4*q16 + r][n0 + m16] = f2b(ka[r]);
    }

    // forward
    f4v hreg[3][2], pacc[2];
    for (int l = 0; l < 4; ++l){
        __syncthreads();                       // xl[l] writes visible
        s8v xa[8];
        #pragma unroll
        for (int i = 0; i < 8; ++i)
            xa[i] = *(const s8v*)(&xl[l][m16][q16*8 + i*32]);
        const unsigned short* Wt = WTb + (size_t)l*DDn;
        #pragma unroll
        for (int t = 0; t < 2; ++t){
            int n0 = w*32 + t*16;
            f4v acc = {0.f,0.f,0.f,0.f};
            const unsigned short* br = Wt + (size_t)(n0 + m16)*256 + q16*8;
            #pragma unroll
            for (int i = 0; i < 8; ++i){
                s8v b = *(const s8v*)(br + i*32);
                acc = __builtin_amdgcn_mfma_f32_16x16x32_bf16(xa[i], b, acc, 0, 0, 0);
            }
            if (l < 3){
                hreg[l][t] = acc;
                #pragma unroll
                for (int r = 0; r < 4; ++r)
                    xl[l+1][4*q16 + r][n0 + m16] = f2b(silu_(acc[r]));
            } else {
                pacc[t] = acc;
            }
        }
    }

    // G_pred = sc*(pred - V)
    #pragma unroll
    for (int t = 0; t < 2; ++t){
        int n0 = w*32 + t*16;
        #pragma unroll
        for (int r = 0; r < 4; ++r)
            Gs[4*q16 + r][n0 + m16] = f2b(sc * (pacc[t][r] - vacc[t][r]));
    }
    __syncthreads();

    // backward: for l=3..0: wgrad_l (supb layer l, transposed [n][k]); then dgrad
    for (int l = 3; l >= 0; --l){
        // wgrad A-frag: G^T rows 32w..32w+31
        s8v ga;
        #pragma unroll
        for (int j = 0; j < 8; ++j)
            ga[j] = (short)Gs[q32*8 + j][w*32 + m32];
        unsigned short* outL = supb + ((size_t)g*4 + l)*DDn;
        #pragma unroll
        for (int t = 0; t < 4; ++t){
            int m0 = bh*128 + t*32;
            s8v xb;
            #pragma unroll
            for (int j = 0; j < 8; ++j)
                xb[j] = (short)xl[l][q32*8 + j][m0 + m32];
            f16v z;
            #pragma unroll
            for (int i = 0; i < 16; ++i) z[i] = 0.f;
            f16v wacc = __builtin_amdgcn_mfma_f32_32x32x16_bf16(ga, xb, z, 0, 0, 0);
            #pragma unroll
            for (int rg = 0; rg < 16; ++rg){
                int row = w*32 + (rg & 3) + 8*(rg >> 2) + 4*q32;
                outL[(size_t)row*256 + m0 + m32] = f2b(wacc[rg]);
            }
        }
        if (l > 0){
            s8v gfa[8];
            #pragma unroll
            for (int i = 0; i < 8; ++i)
                gfa[i] = *(const s8v*)(&Gs[m16][q16*8 + i*32]);
            const unsigned short* Wr = Wb + (size_t)(l-1)*DDn;   // W1..W3 at 0..2
            f4v gn[2];
            #pragma unroll
            for (int t = 0; t < 2; ++t){
                int n0 = w*32 + t*16;
                f4v acc = {0.f,0.f,0.f,0.f};
                const unsigned short* br = Wr + (size_t)(n0 + m16)*256 + q16*8;
                #pragma unroll
                for (int i = 0; i < 8; ++i){
                    s8v b = *(const s8v*)(br + i*32);
                    acc = __builtin_amdgcn_mfma_f32_16x16x32_bf16(gfa[i], b, acc, 0, 0, 0);
                }
                #pragma unroll
                for (int r = 0; r < 4; ++r)
                    gn[t][r] = acc[r] * dsilu_(hreg[l-1][t][r]);
            }
            __syncthreads();     // everyone done reading Gs
            #pragma unroll
            for (int t = 0; t < 2; ++t){
                int n0 = w*32 + t*16;
                #pragma unroll
                for (int r = 0; r < 4; ++r)
                    Gs[4*q16 + r][n0 + m16] = f2b(gn[t][r]);
            }
            __syncthreads();
        }
    }
}

// ---- fused momentum+decay scans, in place, bf16, ushort4-vectorized ----
__global__ __launch_bounds__(256) void kscan(unsigned short* __restrict__ supb,
        const float* __restrict__ momg, const float* __restrict__ decg){
    int p4 = blockIdx.x*256 + threadIdx.x;   // 0..65535, 4 elems each
    int b = blockIdx.y;
    float ms[4] = {0,0,0,0}, us[4] = {0,0,0,0};
    unsigned short* base = supb + (size_t)b*Nn*PPn + (size_t)p4*4;
    for (int n = 0; n < Nn; ++n){
        int gg = b*Nn + n;
        float mo = momg[gg], de = 1.f - decg[gg];
        ushort4 v = *(ushort4*)(base + (size_t)n*PPn);
        float s0 = b2f(v.x), s1 = b2f(v.y), s2 = b2f(v.z), s3 = b2f(v.w);
        ms[0] = mo*ms[0] + s0; us[0] = de*us[0] + ms[0];
        ms[1] = mo*ms[1] + s1; us[1] = de*us[1] + ms[1];
        ms[2] = mo*ms[2] + s2; us[2] = de*us[2] + ms[2];
        ms[3] = mo*ms[3] + s3; us[3] = de*us[3] + ms[3];
        v.x = f2b(us[0]); v.y = f2b(us[1]); v.z = f2b(us[2]); v.w = f2b(us[3]);
        *(ushort4*)(base + (size_t)n*PPn) = v;
    }
}

// ---- fused retrieve: q-proj + 4 fast-weight layers + post-norm + shift ----
__global__ __launch_bounds__(512, 1) void kretr(const unsigned short* __restrict__ rnb,
        const unsigned short* __restrict__ WqTb, const unsigned short* __restrict__ WTb,
        const unsigned short* __restrict__ supb, const float* __restrict__ wpost,
        float* __restrict__ out){
    __shared__ unsigned short xs[16][XP];
    __shared__ float red[8][16];
    __shared__ float rs[16];
    int tid = threadIdx.x, w = tid >> 6, lane = tid & 63;
    int m16 = lane & 15, q16 = lane >> 4;
    int g = blockIdx.x, b = g >> 6, nl = g & 63;

    // q projection (no activation)
    {
        s8v af[8];
        const unsigned short* arow = rnb + (size_t)g*4096 + m16*256 + q16*8;
        #pragma unroll
        for (int i = 0; i < 8; ++i) af[i] = *(const s8v*)(arow + i*32);
        #pragma unroll
        for (int t = 0; t < 2; ++t){
            int n0 = w*32 + t*16;
            f4v acc = {0.f,0.f,0.f,0.f};
            const unsigned short* br = WqTb + (size_t)(n0 + m16)*256 + q16*8;
            #pragma unroll
            for (int i = 0; i < 8; ++i){
                s8v bb = *(const s8v*)(br + i*32);
                acc = __builtin_amdgcn_mfma_f32_16x16x32_bf16(af[i], bb, acc, 0, 0, 0);
            }
            #pragma unroll
            for (int r = 0; r < 4; ++r) xs[4*q16 + r][n0 + m16] = f2b(acc[r]);
        }
    }

    f4v facc[2];
    for (int l = 0; l < 4; ++l){
        __syncthreads();                          // writes visible
        s8v xa[8];
        #pragma unroll
        for (int i = 0; i < 8; ++i)
            xa[i] = *(const s8v*)(&xs[m16][q16*8 + i*32]);
        __syncthreads();                          // all reads done before overwrite
        const unsigned short* Wt = WTb + (size_t)l*DDn;
        const unsigned short* Ut = supb + ((size_t)g*4 + l)*DDn;
        #pragma unroll
        for (int t = 0; t < 2; ++t){
            int n0 = w*32 + t*16;
            f4v acc = {0.f,0.f,0.f,0.f};
            const unsigned short* brW = Wt + (size_t)(n0 + m16)*256 + q16*8;
            const unsigned short* brU = Ut + (size_t)(n0 + m16)*256 + q16*8;
            #pragma unroll
            for (int i = 0; i < 8; ++i){
                s8v bW = *(const s8v*)(brW + i*32);
                s8v bU = *(const s8v*)(brU + i*32);
                acc = __builtin_amdgcn_mfma_f32_16x16x32_bf16(xa[i], bW, acc, 0, 0, 0);
                acc = __builtin_amdgcn_mfma_f32_16x16x32_bf16(xa[i], bU, acc, 0, 0, 0);
            }
            if (l < 3){
                #pragma unroll
                for (int r = 0; r < 4; ++r)
                    xs[4*q16 + r][n0 + m16] = f2b(silu_(acc[r]));
            } else {
                facc[t] = acc;
            }
        }
    }

    // post rmsnorm over d (rows c = 4*q16+r)
    float part[4] = {0,0,0,0};
    #pragma unroll
    for (int t = 0; t < 2; ++t)
        #pragma unroll
        for (int r = 0; r < 4; ++r) part[r] += facc[t][r]*facc[t][r];
    #pragma unroll
    for (int off = 1; off < 16; off <<= 1)
        #pragma unroll
        for (int r = 0; r < 4; ++r) part[r] += __shfl_xor(part[r], off, 64);
    if (m16 == 0)
        #pragma unroll
        for (int r = 0; r < 4; ++r) red[w][4*q16 + r] = part[r];
    __syncthreads();
    if (tid < 16){
        float s = 0.f;
        #pragma unroll
        for (int ww = 0; ww < 8; ++ww) s += red[ww][tid];
        rs[tid] = rsqrtf(s*(1.f/256.f) + EPSf);
    }
    __syncthreads();
    #pragma unroll
    for (int t = 0; t < 2; ++t){
        int d = w*32 + t*16 + m16;
        float wp = wpost[d];
        #pragma unroll
        for (int r = 0; r < 4; ++r){
            int c = 4*q16 + r;
            int tp = nl*16 + c + 15;
            if (tp < 1024)
                out[((size_t)b*1024 + tp)*256 + d] = facc[t][r]*rs[c]*wp;
        }
    }
    if (nl == 0){
        for (int idx = tid; idx < 15*256; idx += 512)
            out[(size_t)b*262144 + idx] = 0.f;
    }
}

extern "C" void kernel_launch(void* const* d_in, const int* in_sizes, int n_in,
                              void* d_out, int out_size, void* d_ws, size_t ws_size,
                              hipStream_t stream) {
    const float* seq     = (const float*)d_in[0];
    const float* w_store = (const float*)d_in[1];
    const float* w_retr  = (const float*)d_in[2];
    const float* w_post  = (const float*)d_in[3];
    const float* Wq      = (const float*)d_in[4];
    const float* Wkv     = (const float*)d_in[5];
    const float* w_adapt = (const float*)d_in[6];
    const float* w_mom   = (const float*)d_in[7];
    const float* w_decay = (const float*)d_in[8];
    const float* W0      = (const float*)d_in[9];
    const float* W1      = (const float*)d_in[10];
    const float* W2      = (const float*)d_in[11];
    const float* W3      = (const float*)d_in[12];

    // workspace: small f32 arrays first (keep 16B alignment), then bf16 arrays
    float* lrg  = (float*)d_ws;               // 128
    float* momg = lrg + NCn;                  // 128
    float* decg = momg + NCn;                 // 128
    unsigned short* ub    = (unsigned short*)(decg + NCn + 64);  // align pad
    unsigned short* snb   = ub;                        // 524288
    unsigned short* rnb   = snb   + (size_t)NCn*4096;  // 524288
    unsigned short* WTb   = rnb   + (size_t)NCn*4096;  // 4*65536
    unsigned short* Wb    = WTb   + 4*(size_t)DDn;     // 3*65536 (W1..W3)
    unsigned short* WqTb  = Wb    + 3*(size_t)DDn;     // 65536
    unsigned short* WkvTb = WqTb  + (size_t)DDn;       // 131072
    unsigned short* supb  = WkvTb + 2*(size_t)DDn;     // 33554432 (67MB)

    kwcast<<<dim3(256, 10), 256, 0, stream>>>(Wq, Wkv, W0, W1, W2, W3,
                                              WTb, Wb, WqTb, WkvTb);
    kprep <<<dim3(NCn),     256, 0, stream>>>(seq, w_store, w_retr, w_adapt, w_mom,
                                              w_decay, snb, rnb, lrg, momg, decg);
    kstore<<<dim3(2, NCn),  512, 0, stream>>>(snb, WkvTb, WTb, Wb, lrg, supb);
    kscan <<<dim3(256, 2),  256, 0, stream>>>(supb, momg, decg);
    kretr <<<dim3(NCn),     512, 0, stream>>>(rnb, WqTb, WTb, supb, w_post,
                                              (float*)d_out);
}

// Round 4
// 208.785 us; speedup vs baseline: 2.4142x; 1.0263x over previous
//
#include <hip/hip_runtime.h>
#include <hip/hip_bf16.h>

typedef __attribute__((ext_vector_type(8)))  short s8v;   // 8 bf16 (4 VGPR)
typedef __attribute__((ext_vector_type(4)))  float f4v;   // 16x16 C/D
typedef __attribute__((ext_vector_type(16))) float f16v;  // 32x32 C/D

constexpr int Dd   = 256;
constexpr int Nn   = 64;
constexpr int NCn  = 128;
constexpr int DDn  = 65536;
constexpr int XP   = 264;             // padded LDS row (bf16 elems)
constexpr float EPSf = 1.1920929e-07f;

__device__ __forceinline__ float sigm(float x){ return 1.0f/(1.0f + expf(-x)); }
__device__ __forceinline__ float silu_(float x){ return x * sigm(x); }
__device__ __forceinline__ float dsilu_(float x){ float s = sigm(x); return s*(1.0f + x*(1.0f - s)); }

__device__ __forceinline__ unsigned short f2b(float x){
    __hip_bfloat16 b = __float2bfloat16(x);
    unsigned short u; __builtin_memcpy(&u, &b, 2); return u;
}

__device__ __forceinline__ float block_sum(float v, float* red){
    #pragma unroll
    for (int off = 32; off; off >>= 1) v += __shfl_down(v, off, 64);
    if ((threadIdx.x & 63) == 0) red[threadIdx.x >> 6] = v;
    __syncthreads();
    float r = red[0] + red[1] + red[2] + red[3];
    __syncthreads();
    return r;
}

// ---- weights -> bf16, both layouts ----
__global__ __launch_bounds__(256) void kwcast(const float* __restrict__ Wq,
        const float* __restrict__ Wkv, const float* __restrict__ W0,
        const float* __restrict__ W1, const float* __restrict__ W2,
        const float* __restrict__ W3, unsigned short* __restrict__ WTb,
        unsigned short* __restrict__ Wb, unsigned short* __restrict__ WqTb,
        unsigned short* __restrict__ WkvTb){
    int j = blockIdx.x, m = blockIdx.y, k = threadIdx.x;
    if (m < 4){
        const float* W = (m==0)?W0:(m==1)?W1:(m==2)?W2:W3;
        WTb[(size_t)m*DDn + j*256 + k] = f2b(W[(size_t)k*256 + j]);
    } else if (m < 7){
        const float* W = (m==4)?W1:(m==5)?W2:W3;
        Wb[(size_t)(m-4)*DDn + j*256 + k] = f2b(W[(size_t)j*256 + k]);
    } else if (m == 7){
        WqTb[(size_t)j*256 + k] = f2b(Wq[(size_t)k*256 + j]);
    } else {
        int r = j + (m-8)*256;
        WkvTb[(size_t)r*256 + k] = f2b(Wkv[(size_t)k*512 + r]);
    }
}

// ---- per-token norms (2048 blocks) + chunk-mean partials via atomics ----
__global__ __launch_bounds__(256) void knorm(const float* __restrict__ seq,
        const float* __restrict__ wsn, const float* __restrict__ wrn,
        unsigned short* __restrict__ snb, unsigned short* __restrict__ rnb,
        float* __restrict__ cmacc){
    __shared__ float red[4];
    int t = blockIdx.x, d = threadIdx.x;
    int b = t >> 10, tl = t & 1023, g = t >> 4, c = tl & 15;
    float x = seq[(size_t)t*256 + d];
    float ss = block_sum(x*x, red);
    float v = x * rsqrtf(ss*(1.f/256.f) + EPSf) * wsn[d];
    snb[(size_t)g*4096 + c*256 + d] = f2b(v);
    atomicAdd(&cmacc[g*256 + d], v);
    float y = 0.f;
    if (tl <= 1008){                  // block-uniform
        float xv = seq[((size_t)b*1024 + tl + 15)*256 + d];
        float s2 = block_sum(xv*xv, red);
        y = xv * rsqrtf(s2*(1.f/256.f) + EPSf) * wrn[d];
    }
    rnb[(size_t)g*4096 + c*256 + d] = f2b(y);
}

__global__ __launch_bounds__(256) void kgates(const float* __restrict__ cmacc,
        const float* __restrict__ wa, const float* __restrict__ wm,
        const float* __restrict__ wdk, float* __restrict__ lrg,
        float* __restrict__ momg, float* __restrict__ decg){
    __shared__ float red[4];
    int g = blockIdx.x, d = threadIdx.x;
    float cm = cmacc[g*256 + d] * (1.f/16.f);
    float da = block_sum(cm*wa[d], red);
    float dm = block_sum(cm*wm[d], red);
    float dc = block_sum(cm*wdk[d], red);
    if (d == 0){ lrg[g] = sigm(da); momg[g] = sigm(dm); decg[g] = sigm(dc); }
}

// ---- fwd + bwd dgrads only; writes transposed activations XT and grads GT (8MB) ----
// grid (2, 128): bh=0 writes XT (fwd only), bh=1 writes GT (fwd+bwd)
__global__ __launch_bounds__(512, 1) void kfb(const unsigned short* __restrict__ snb,
        const unsigned short* __restrict__ WkvTb, const unsigned short* __restrict__ WTb,
        const unsigned short* __restrict__ Wb, const float* __restrict__ lrg,
        unsigned short* __restrict__ XT, unsigned short* __restrict__ GT){
    __shared__ unsigned short xl[4][16][XP];
    __shared__ unsigned short Gs[16][XP];
    int tid = threadIdx.x, w = tid >> 6, lane = tid & 63;
    int m16 = lane & 15, q16 = lane >> 4;
    int g = blockIdx.y, bh = blockIdx.x;
    float sc = -2.f * lrg[g] * (1.f/256.f);

    s8v af[8];
    const unsigned short* arow = snb + (size_t)g*4096 + m16*256 + q16*8;
    #pragma unroll
    for (int i = 0; i < 8; ++i) af[i] = *(const s8v*)(arow + i*32);

    // proj: K -> xl[0], V -> regs
    f4v vacc[2];
    #pragma unroll
    for (int t = 0; t < 2; ++t){
        int n0 = w*32 + t*16;
        f4v ka = {0.f,0.f,0.f,0.f}, va = {0.f,0.f,0.f,0.f};
        const unsigned short* brK = WkvTb + (size_t)(n0 + m16)*256 + q16*8;
        const unsigned short* brV = WkvTb + (size_t)(256 + n0 + m16)*256 + q16*8;
        #pragma unroll
        for (int i = 0; i < 8; ++i){
            s8v bK = *(const s8v*)(brK + i*32);
            s8v bV = *(const s8v*)(brV + i*32);
            ka = __builtin_amdgcn_mfma_f32_16x16x32_bf16(af[i], bK, ka, 0, 0, 0);
            va = __builtin_amdgcn_mfma_f32_16x16x32_bf16(af[i], bV, va, 0, 0, 0);
        }
        vacc[t] = va;
        #pragma unroll
        for (int r = 0; r < 4; ++r) xl[0][4*q16 + r][n0 + m16] = f2b(ka[r]);
    }

    // fwd layers 0..2 (producing xl[1..3])
    f4v hreg[3][2];
    for (int l = 0; l < 3; ++l){
        __syncthreads();
        s8v xa[8];
        #pragma unroll
        for (int i = 0; i < 8; ++i)
            xa[i] = *(const s8v*)(&xl[l][m16][q16*8 + i*32]);
        const unsigned short* Wt = WTb + (size_t)l*DDn;
        #pragma unroll
        for (int t = 0; t < 2; ++t){
            int n0 = w*32 + t*16;
            f4v acc = {0.f,0.f,0.f,0.f};
            const unsigned short* br = Wt + (size_t)(n0 + m16)*256 + q16*8;
            #pragma unroll
            for (int i = 0; i < 8; ++i){
                s8v b = *(const s8v*)(br + i*32);
                acc = __builtin_amdgcn_mfma_f32_16x16x32_bf16(xa[i], b, acc, 0, 0, 0);
            }
            hreg[l][t] = acc;
            #pragma unroll
            for (int r = 0; r < 4; ++r)
                xl[l+1][4*q16 + r][n0 + m16] = f2b(silu_(acc[r]));
        }
    }
    __syncthreads();     // xl[3] ready

    if (bh == 0){
        // write XT[l][g][d][c] (transposed activations)
        int d = tid & 255, half = tid >> 8;
        #pragma unroll
        for (int l = 0; l < 4; ++l){
            s8v v;
            #pragma unroll
            for (int j = 0; j < 8; ++j) v[j] = (short)xl[l][half*8 + j][d];
            *(s8v*)(XT + (((size_t)l*128 + g)*256 + d)*16 + half*8) = v;
        }
        return;
    }

    // layer 3 (pred)
    {
        s8v xa[8];
        #pragma unroll
        for (int i = 0; i < 8; ++i)
            xa[i] = *(const s8v*)(&xl[3][m16][q16*8 + i*32]);
        const unsigned short* Wt = WTb + (size_t)3*DDn;
        #pragma unroll
        for (int t = 0; t < 2; ++t){
            int n0 = w*32 + t*16;
            f4v acc = {0.f,0.f,0.f,0.f};
            const unsigned short* br = Wt + (size_t)(n0 + m16)*256 + q16*8;
            #pragma unroll
            for (int i = 0; i < 8; ++i){
                s8v b = *(const s8v*)(br + i*32);
                acc = __builtin_amdgcn_mfma_f32_16x16x32_bf16(xa[i], b, acc, 0, 0, 0);
            }
            #pragma unroll
            for (int r = 0; r < 4; ++r)
                Gs[4*q16 + r][n0 + m16] = f2b(sc * (acc[r] - vacc[t][r]));
        }
    }
    __syncthreads();
    {   // write GT[3]
        int d = tid & 255, half = tid >> 8;
        s8v v;
        #pragma unroll
        for (int j = 0; j < 8; ++j) v[j] = (short)Gs[half*8 + j][d];
        *(s8v*)(GT + (((size_t)3*128 + g)*256 + d)*16 + half*8) = v;
    }

    for (int l = 3; l >= 1; --l){
        s8v gfa[8];
        #pragma unroll
        for (int i = 0; i < 8; ++i)
            gfa[i] = *(const s8v*)(&Gs[m16][q16*8 + i*32]);
        const unsigned short* Wr = Wb + (size_t)(l-1)*DDn;
        f4v gn[2];
        #pragma unroll
        for (int t = 0; t < 2; ++t){
            int n0 = w*32 + t*16;
            f4v acc = {0.f,0.f,0.f,0.f};
            const unsigned short* br = Wr + (size_t)(n0 + m16)*256 + q16*8;
            #pragma unroll
            for (int i = 0; i < 8; ++i){
                s8v b = *(const s8v*)(br + i*32);
                acc = __builtin_amdgcn_mfma_f32_16x16x32_bf16(gfa[i], b, acc, 0, 0, 0);
            }
            #pragma unroll
            for (int r = 0; r < 4; ++r)
                gn[t][r] = acc[r] * dsilu_(hreg[l-1][t][r]);
        }
        __syncthreads();     // all reads of Gs done
        #pragma unroll
        for (int t = 0; t < 2; ++t){
            int n0 = w*32 + t*16;
            #pragma unroll
            for (int r = 0; r < 4; ++r)
                Gs[4*q16 + r][n0 + m16] = f2b(gn[t][r]);
        }
        __syncthreads();
        {   // write GT[l-1]
            int d = tid & 255, half = tid >> 8;
            s8v v;
            #pragma unroll
            for (int j = 0; j < 8; ++j) v[j] = (short)Gs[half*8 + j][d];
            *(s8v*)(GT + (((size_t)(l-1)*128 + g)*256 + d)*16 + half*8) = v;
        }
    }
}

// ---- fused outer-product + momentum + decay scans -> updates (bf16) ----
// grid (64 tiles, 4 layers, 2 batches), 64 threads (1 wave, 32x32 tile)
__global__ __launch_bounds__(64, 1) void kupd(const unsigned short* __restrict__ XT,
        const unsigned short* __restrict__ GT, const float* __restrict__ momg,
        const float* __restrict__ decg, unsigned short* __restrict__ supb){
    int lane = threadIdx.x, m32 = lane & 31, q32 = lane >> 5;
    int tile = blockIdx.x, l = blockIdx.y, b = blockIdx.z;
    int r0 = (tile >> 3)*32, c0 = (tile & 7)*32;
    const unsigned short* gbase = GT + (size_t)l*128*4096 + (size_t)(r0 + m32)*16 + q32*8;
    const unsigned short* xbase = XT + (size_t)l*128*4096 + (size_t)(c0 + m32)*16 + q32*8;
    float ms[16], us[16];
    #pragma unroll
    for (int i = 0; i < 16; ++i){ ms[i] = 0.f; us[i] = 0.f; }
    for (int n = 0; n < 64; ++n){
        int gg = b*64 + n;
        s8v ga = *(const s8v*)(gbase + (size_t)gg*4096);
        s8v xb = *(const s8v*)(xbase + (size_t)gg*4096);
        f16v z;
        #pragma unroll
        for (int i = 0; i < 16; ++i) z[i] = 0.f;
        f16v s = __builtin_amdgcn_mfma_f32_32x32x16_bf16(ga, xb, z, 0, 0, 0);
        float mo = momg[gg], de = 1.f - decg[gg];
        unsigned short* outp = supb + ((size_t)gg*4 + l)*DDn + c0 + m32;
        #pragma unroll
        for (int rg = 0; rg < 16; ++rg){
            ms[rg] = mo*ms[rg] + s[rg];
            us[rg] = de*us[rg] + ms[rg];
            int row = r0 + (rg & 3) + 8*(rg >> 2) + 4*q32;
            outp[(size_t)row*256] = f2b(us[rg]);
        }
    }
}

// ---- fused retrieve: q-proj + 4 fast-weight layers + post-norm + shift ----
__global__ __launch_bounds__(512, 1) void kretr(const unsigned short* __restrict__ rnb,
        const unsigned short* __restrict__ WqTb, const unsigned short* __restrict__ WTb,
        const unsigned short* __restrict__ supb, const float* __restrict__ wpost,
        float* __restrict__ out){
    __shared__ unsigned short xs[16][XP];
    __shared__ float red[8][16];
    __shared__ float rs[16];
    int tid = threadIdx.x, w = tid >> 6, lane = tid & 63;
    int m16 = lane & 15, q16 = lane >> 4;
    int g = blockIdx.x, b = g >> 6, nl = g & 63;

    {
        s8v af[8];
        const unsigned short* arow = rnb + (size_t)g*4096 + m16*256 + q16*8;
        #pragma unroll
        for (int i = 0; i < 8; ++i) af[i] = *(const s8v*)(arow + i*32);
        #pragma unroll
        for (int t = 0; t < 2; ++t){
            int n0 = w*32 + t*16;
            f4v acc = {0.f,0.f,0.f,0.f};
            const unsigned short* br = WqTb + (size_t)(n0 + m16)*256 + q16*8;
            #pragma unroll
            for (int i = 0; i < 8; ++i){
                s8v bb = *(const s8v*)(br + i*32);
                acc = __builtin_amdgcn_mfma_f32_16x16x32_bf16(af[i], bb, acc, 0, 0, 0);
            }
            #pragma unroll
            for (int r = 0; r < 4; ++r) xs[4*q16 + r][n0 + m16] = f2b(acc[r]);
        }
    }

    f4v facc[2];
    for (int l = 0; l < 4; ++l){
        __syncthreads();
        s8v xa[8];
        #pragma unroll
        for (int i = 0; i < 8; ++i)
            xa[i] = *(const s8v*)(&xs[m16][q16*8 + i*32]);
        __syncthreads();
        const unsigned short* Wt = WTb + (size_t)l*DDn;
        const unsigned short* Ut = supb + ((size_t)g*4 + l)*DDn;
        #pragma unroll
        for (int t = 0; t < 2; ++t){
            int n0 = w*32 + t*16;
            f4v acc = {0.f,0.f,0.f,0.f};
            const unsigned short* brW = Wt + (size_t)(n0 + m16)*256 + q16*8;
            const unsigned short* brU = Ut + (size_t)(n0 + m16)*256 + q16*8;
            #pragma unroll
            for (int i = 0; i < 8; ++i){
                s8v bW = *(const s8v*)(brW + i*32);
                s8v bU = *(const s8v*)(brU + i*32);
                acc = __builtin_amdgcn_mfma_f32_16x16x32_bf16(xa[i], bW, acc, 0, 0, 0);
                acc = __builtin_amdgcn_mfma_f32_16x16x32_bf16(xa[i], bU, acc, 0, 0, 0);
            }
            if (l < 3){
                #pragma unroll
                for (int r = 0; r < 4; ++r)
                    xs[4*q16 + r][n0 + m16] = f2b(silu_(acc[r]));
            } else {
                facc[t] = acc;
            }
        }
    }

    float part[4] = {0,0,0,0};
    #pragma unroll
    for (int t = 0; t < 2; ++t)
        #pragma unroll
        for (int r = 0; r < 4; ++r) part[r] += facc[t][r]*facc[t][r];
    #pragma unroll
    for (int off = 1; off < 16; off <<= 1)
        #pragma unroll
        for (int r = 0; r < 4; ++r) part[r] += __shfl_xor(part[r], off, 64);
    if (m16 == 0)
        #pragma unroll
        for (int r = 0; r < 4; ++r) red[w][4*q16 + r] = part[r];
    __syncthreads();
    if (tid < 16){
        float s = 0.f;
        #pragma unroll
        for (int ww = 0; ww < 8; ++ww) s += red[ww][tid];
        rs[tid] = rsqrtf(s*(1.f/256.f) + EPSf);
    }
    __syncthreads();
    #pragma unroll
    for (int t = 0; t < 2; ++t){
        int d = w*32 + t*16 + m16;
        float wp = wpost[d];
        #pragma unroll
        for (int r = 0; r < 4; ++r){
            int c = 4*q16 + r;
            int tp = nl*16 + c + 15;
            if (tp < 1024)
                out[((size_t)b*1024 + tp)*256 + d] = facc[t][r]*rs[c]*wp;
        }
    }
    if (nl == 0){
        for (int idx = tid; idx < 15*256; idx += 512)
            out[(size_t)b*262144 + idx] = 0.f;
    }
}

extern "C" void kernel_launch(void* const* d_in, const int* in_sizes, int n_in,
                              void* d_out, int out_size, void* d_ws, size_t ws_size,
                              hipStream_t stream) {
    const float* seq     = (const float*)d_in[0];
    const float* w_store = (const float*)d_in[1];
    const float* w_retr  = (const float*)d_in[2];
    const float* w_post  = (const float*)d_in[3];
    const float* Wq      = (const float*)d_in[4];
    const float* Wkv     = (const float*)d_in[5];
    const float* w_adapt = (const float*)d_in[6];
    const float* w_mom   = (const float*)d_in[7];
    const float* w_decay = (const float*)d_in[8];
    const float* W0      = (const float*)d_in[9];
    const float* W1      = (const float*)d_in[10];
    const float* W2      = (const float*)d_in[11];
    const float* W3      = (const float*)d_in[12];

    float* lrg   = (float*)d_ws;                  // 128
    float* momg  = lrg + NCn;                     // 128
    float* decg  = momg + NCn;                    // 128
    float* cmacc = decg + NCn;                    // 128*256
    unsigned short* snb   = (unsigned short*)(cmacc + NCn*256);
    unsigned short* rnb   = snb   + (size_t)NCn*4096;   // 524288 each
    unsigned short* WTb   = rnb   + (size_t)NCn*4096;   // 4*DDn
    unsigned short* Wb    = WTb   + 4*(size_t)DDn;      // 3*DDn
    unsigned short* WqTb  = Wb    + 3*(size_t)DDn;      // DDn
    unsigned short* WkvTb = WqTb  + (size_t)DDn;        // 2*DDn
    unsigned short* XT    = WkvTb + 2*(size_t)DDn;      // 4*128*4096 = 2M
    unsigned short* GT    = XT    + (size_t)4*NCn*4096; // 2M
    unsigned short* supb  = GT    + (size_t)4*NCn*4096; // 33.5M (67MB)

    hipMemsetAsync(cmacc, 0, (size_t)NCn*256*sizeof(float), stream);
    kwcast<<<dim3(256, 10), 256, 0, stream>>>(Wq, Wkv, W0, W1, W2, W3,
                                              WTb, Wb, WqTb, WkvTb);
    knorm <<<dim3(2048),    256, 0, stream>>>(seq, w_store, w_retr, snb, rnb, cmacc);
    kgates<<<dim3(NCn),     256, 0, stream>>>(cmacc, w_adapt, w_mom, w_decay,
                                              lrg, momg, decg);
    kfb   <<<dim3(2, NCn),  512, 0, stream>>>(snb, WkvTb, WTb, Wb, lrg, XT, GT);
    kupd  <<<dim3(64, 4, 2), 64, 0, stream>>>(XT, GT, momg, decg, supb);
    kretr <<<dim3(NCn),     512, 0, stream>>>(rnb, WqTb, WTb, supb, w_post,
                                              (float*)d_out);
}

// Round 5
// 198.111 us; speedup vs baseline: 2.5443x; 1.0539x over previous
//
#include <hip/hip_runtime.h>
#include <hip/hip_bf16.h>

typedef __attribute__((ext_vector_type(8)))  short s8v;   // 8 bf16 (4 VGPR)
typedef __attribute__((ext_vector_type(4)))  float f4v;   // 16x16 C/D
typedef __attribute__((ext_vector_type(16))) float f16v;  // 32x32 C/D

constexpr int Dd   = 256;
constexpr int Nn   = 64;
constexpr int NCn  = 128;
constexpr int DDn  = 65536;
constexpr int XP   = 264;             // padded LDS row (bf16 elems)
constexpr float EPSf = 1.1920929e-07f;

__device__ __forceinline__ float sigm(float x){ return 1.0f/(1.0f + expf(-x)); }
__device__ __forceinline__ float silu_(float x){ return x * sigm(x); }
__device__ __forceinline__ float dsilu_(float x){ float s = sigm(x); return s*(1.0f + x*(1.0f - s)); }

__device__ __forceinline__ unsigned short f2b(float x){
    __hip_bfloat16 b = __float2bfloat16(x);
    unsigned short u; __builtin_memcpy(&u, &b, 2); return u;
}
__device__ __forceinline__ float b2f(unsigned short u){
    __hip_bfloat16 b; __builtin_memcpy(&b, &u, 2); return __bfloat162float(b);
}

__device__ __forceinline__ float block_sum(float v, float* red){
    #pragma unroll
    for (int off = 32; off; off >>= 1) v += __shfl_down(v, off, 64);
    if ((threadIdx.x & 63) == 0) red[threadIdx.x >> 6] = v;
    __syncthreads();
    float r = red[0] + red[1] + red[2] + red[3];
    __syncthreads();
    return r;
}

// ---- coalesced tiled transposes fp32 -> bf16 ----
// z=0..3: W0..W3 -> WTb[z]; z=4: Wq -> WqTb; z=5: Wkv(256x512) -> WkvTb(512x256)
__global__ __launch_bounds__(256) void ktrans(const float* __restrict__ Wq,
        const float* __restrict__ Wkv, const float* __restrict__ W0,
        const float* __restrict__ W1, const float* __restrict__ W2,
        const float* __restrict__ W3, unsigned short* __restrict__ WTb,
        unsigned short* __restrict__ WqTb, unsigned short* __restrict__ WkvTb){
    __shared__ float tl[32][33];
    int z = blockIdx.z;
    if (z != 5 && blockIdx.y >= 8) return;
    const float* S; unsigned short* T; int C;   // source is 256 x C
    if (z < 4){ S = (z==0)?W0:(z==1)?W1:(z==2)?W2:W3; T = WTb + (size_t)z*DDn; C = 256; }
    else if (z == 4){ S = Wq; T = WqTb; C = 256; }
    else { S = Wkv; T = WkvTb; C = 512; }
    int k0 = blockIdx.x*32, j0 = blockIdx.y*32;
    int tx = threadIdx.x & 31, ty = threadIdx.x >> 5;   // ty 0..7
    #pragma unroll
    for (int p = 0; p < 4; ++p)
        tl[ty + 8*p][tx] = S[(size_t)(k0 + ty + 8*p)*C + j0 + tx];
    __syncthreads();
    #pragma unroll
    for (int p = 0; p < 4; ++p)
        T[(size_t)(j0 + ty + 8*p)*256 + k0 + tx] = f2b(tl[tx][ty + 8*p]);
}

// ---- vectorized cast-copy W1..W3 -> Wb (row-major bf16) ----
__global__ __launch_bounds__(256) void kcopy(const float* __restrict__ W1,
        const float* __restrict__ W2, const float* __restrict__ W3,
        unsigned short* __restrict__ Wb){
    int z = blockIdx.z;
    const float* S = (z==0)?W1:(z==1)?W2:W3;
    size_t idx = (size_t)blockIdx.x*1024 + threadIdx.x*4;
    float4 v = *(const float4*)(S + idx);
    ushort4 u; u.x = f2b(v.x); u.y = f2b(v.y); u.z = f2b(v.z); u.w = f2b(v.w);
    *(ushort4*)(Wb + (size_t)z*DDn + idx) = u;
}

// ---- per-token norm (one reduction), scatter sn + shifted rn ----
__global__ __launch_bounds__(256) void knorm(const float* __restrict__ seq,
        const float* __restrict__ wsn, const float* __restrict__ wrn,
        unsigned short* __restrict__ snb, unsigned short* __restrict__ rnb){
    __shared__ float red[4];
    int t = blockIdx.x, d = threadIdx.x;
    int b = t >> 10, tl = t & 1023, g = t >> 4, c = tl & 15;
    float x = seq[(size_t)t*256 + d];
    float ss = block_sum(x*x, red);
    float xr = x * rsqrtf(ss*(1.f/256.f) + EPSf);
    snb[(size_t)g*4096 + c*256 + d] = f2b(xr*wsn[d]);
    if (tl >= 15){
        int tl2 = tl - 15, g2 = b*64 + (tl2 >> 4), c2 = tl2 & 15;
        rnb[(size_t)g2*4096 + c2*256 + d] = f2b(xr*wrn[d]);
    }
    if (tl >= 1009)
        rnb[(size_t)g*4096 + c*256 + d] = 0;
}

// ---- gates from bf16 sn chunk means ----
__global__ __launch_bounds__(256) void kgates(const unsigned short* __restrict__ snb,
        const float* __restrict__ wa, const float* __restrict__ wm,
        const float* __restrict__ wdk, float* __restrict__ lrg,
        float* __restrict__ momg, float* __restrict__ decg){
    __shared__ float red[4];
    int g = blockIdx.x, d = threadIdx.x;
    float a = 0.f;
    #pragma unroll
    for (int c = 0; c < 16; ++c) a += b2f(snb[(size_t)g*4096 + c*256 + d]);
    float cm = a * (1.f/16.f);
    float da = block_sum(cm*wa[d], red);
    float dm = block_sum(cm*wm[d], red);
    float dc = block_sum(cm*wdk[d], red);
    if (d == 0){ lrg[g] = sigm(da); momg[g] = sigm(dm); decg[g] = sigm(dc); }
}

// ---- fwd + bwd dgrads; writes transposed activations XT and grads GT (8MB) ----
// grid (2, 128): bh=0 writes XT (fwd only), bh=1 writes GT (fwd+bwd)
__global__ __launch_bounds__(512, 1) void kfb(const unsigned short* __restrict__ snb,
        const unsigned short* __restrict__ WkvTb, const unsigned short* __restrict__ WTb,
        const unsigned short* __restrict__ Wb, const float* __restrict__ lrg,
        unsigned short* __restrict__ XT, unsigned short* __restrict__ GT){
    __shared__ unsigned short xl[4][16][XP];
    __shared__ unsigned short Gs[16][XP];
    int tid = threadIdx.x, w = tid >> 6, lane = tid & 63;
    int m16 = lane & 15, q16 = lane >> 4;
    int g = blockIdx.y, bh = blockIdx.x;
    float sc = -2.f * lrg[g] * (1.f/256.f);

    s8v af[8];
    const unsigned short* arow = snb + (size_t)g*4096 + m16*256 + q16*8;
    #pragma unroll
    for (int i = 0; i < 8; ++i) af[i] = *(const s8v*)(arow + i*32);

    // proj: K -> xl[0], V -> regs
    f4v vacc[2];
    #pragma unroll
    for (int t = 0; t < 2; ++t){
        int n0 = w*32 + t*16;
        f4v ka = {0.f,0.f,0.f,0.f}, va = {0.f,0.f,0.f,0.f};
        const unsigned short* brK = WkvTb + (size_t)(n0 + m16)*256 + q16*8;
        const unsigned short* brV = WkvTb + (size_t)(256 + n0 + m16)*256 + q16*8;
        #pragma unroll
        for (int i = 0; i < 8; ++i){
            s8v bK = *(const s8v*)(brK + i*32);
            s8v bV = *(const s8v*)(brV + i*32);
            ka = __builtin_amdgcn_mfma_f32_16x16x32_bf16(af[i], bK, ka, 0, 0, 0);
            va = __builtin_amdgcn_mfma_f32_16x16x32_bf16(af[i], bV, va, 0, 0, 0);
        }
        vacc[t] = va;
        #pragma unroll
        for (int r = 0; r < 4; ++r) xl[0][4*q16 + r][n0 + m16] = f2b(ka[r]);
    }

    f4v hreg[3][2];
    for (int l = 0; l < 3; ++l){
        __syncthreads();
        s8v xa[8];
        #pragma unroll
        for (int i = 0; i < 8; ++i)
            xa[i] = *(const s8v*)(&xl[l][m16][q16*8 + i*32]);
        const unsigned short* Wt = WTb + (size_t)l*DDn;
        #pragma unroll
        for (int t = 0; t < 2; ++t){
            int n0 = w*32 + t*16;
            f4v acc = {0.f,0.f,0.f,0.f};
            const unsigned short* br = Wt + (size_t)(n0 + m16)*256 + q16*8;
            #pragma unroll
            for (int i = 0; i < 8; ++i){
                s8v b = *(const s8v*)(br + i*32);
                acc = __builtin_amdgcn_mfma_f32_16x16x32_bf16(xa[i], b, acc, 0, 0, 0);
            }
            hreg[l][t] = acc;
            #pragma unroll
            for (int r = 0; r < 4; ++r)
                xl[l+1][4*q16 + r][n0 + m16] = f2b(silu_(acc[r]));
        }
    }
    __syncthreads();     // xl[3] ready

    if (bh == 0){
        int d = tid & 255, half = tid >> 8;
        #pragma unroll
        for (int l = 0; l < 4; ++l){
            s8v v;
            #pragma unroll
            for (int j = 0; j < 8; ++j) v[j] = (short)xl[l][half*8 + j][d];
            *(s8v*)(XT + (((size_t)l*128 + g)*256 + d)*16 + half*8) = v;
        }
        return;
    }

    {   // layer 3 (pred) -> G4
        s8v xa[8];
        #pragma unroll
        for (int i = 0; i < 8; ++i)
            xa[i] = *(const s8v*)(&xl[3][m16][q16*8 + i*32]);
        const unsigned short* Wt = WTb + (size_t)3*DDn;
        #pragma unroll
        for (int t = 0; t < 2; ++t){
            int n0 = w*32 + t*16;
            f4v acc = {0.f,0.f,0.f,0.f};
            const unsigned short* br = Wt + (size_t)(n0 + m16)*256 + q16*8;
            #pragma unroll
            for (int i = 0; i < 8; ++i){
                s8v b = *(const s8v*)(br + i*32);
                acc = __builtin_amdgcn_mfma_f32_16x16x32_bf16(xa[i], b, acc, 0, 0, 0);
            }
            #pragma unroll
            for (int r = 0; r < 4; ++r)
                Gs[4*q16 + r][n0 + m16] = f2b(sc * (acc[r] - vacc[t][r]));
        }
    }
    __syncthreads();
    {
        int d = tid & 255, half = tid >> 8;
        s8v v;
        #pragma unroll
        for (int j = 0; j < 8; ++j) v[j] = (short)Gs[half*8 + j][d];
        *(s8v*)(GT + (((size_t)3*128 + g)*256 + d)*16 + half*8) = v;
    }

    for (int l = 3; l >= 1; --l){
        s8v gfa[8];
        #pragma unroll
        for (int i = 0; i < 8; ++i)
            gfa[i] = *(const s8v*)(&Gs[m16][q16*8 + i*32]);
        const unsigned short* Wr = Wb + (size_t)(l-1)*DDn;
        f4v gn[2];
        #pragma unroll
        for (int t = 0; t < 2; ++t){
            int n0 = w*32 + t*16;
            f4v acc = {0.f,0.f,0.f,0.f};
            const unsigned short* br = Wr + (size_t)(n0 + m16)*256 + q16*8;
            #pragma unroll
            for (int i = 0; i < 8; ++i){
                s8v b = *(const s8v*)(br + i*32);
                acc = __builtin_amdgcn_mfma_f32_16x16x32_bf16(gfa[i], b, acc, 0, 0, 0);
            }
            #pragma unroll
            for (int r = 0; r < 4; ++r)
                gn[t][r] = acc[r] * dsilu_(hreg[l-1][t][r]);
        }
        __syncthreads();
        #pragma unroll
        for (int t = 0; t < 2; ++t){
            int n0 = w*32 + t*16;
            #pragma unroll
            for (int r = 0; r < 4; ++r)
                Gs[4*q16 + r][n0 + m16] = f2b(gn[t][r]);
        }
        __syncthreads();
        {
            int d = tid & 255, half = tid >> 8;
            s8v v;
            #pragma unroll
            for (int j = 0; j < 8; ++j) v[j] = (short)Gs[half*8 + j][d];
            *(s8v*)(GT + (((size_t)(l-1)*128 + g)*256 + d)*16 + half*8) = v;
        }
    }
}

// ---- fused outer-product + momentum + decay scans -> updates (bf16) ----
__global__ __launch_bounds__(64, 1) void kupd(const unsigned short* __restrict__ XT,
        const unsigned short* __restrict__ GT, const float* __restrict__ momg,
        const float* __restrict__ decg, unsigned short* __restrict__ supb){
    int lane = threadIdx.x, m32 = lane & 31, q32 = lane >> 5;
    int tile = blockIdx.x, l = blockIdx.y, b = blockIdx.z;
    int r0 = (tile >> 3)*32, c0 = (tile & 7)*32;
    const unsigned short* gbase = GT + (size_t)l*128*4096 + (size_t)(r0 + m32)*16 + q32*8;
    const unsigned short* xbase = XT + (size_t)l*128*4096 + (size_t)(c0 + m32)*16 + q32*8;
    float ms[16], us[16];
    #pragma unroll
    for (int i = 0; i < 16; ++i){ ms[i] = 0.f; us[i] = 0.f; }
    #pragma unroll 2
    for (int n = 0; n < 64; ++n){
        int gg = b*64 + n;
        s8v ga = *(const s8v*)(gbase + (size_t)gg*4096);
        s8v xb = *(const s8v*)(xbase + (size_t)gg*4096);
        f16v z;
        #pragma unroll
        for (int i = 0; i < 16; ++i) z[i] = 0.f;
        f16v s = __builtin_amdgcn_mfma_f32_32x32x16_bf16(ga, xb, z, 0, 0, 0);
        float mo = momg[gg], de = 1.f - decg[gg];
        unsigned short* outp = supb + ((size_t)gg*4 + l)*DDn + c0 + m32;
        #pragma unroll
        for (int rg = 0; rg < 16; ++rg){
            ms[rg] = mo*ms[rg] + s[rg];
            us[rg] = de*us[rg] + ms[rg];
            int row = r0 + (rg & 3) + 8*(rg >> 2) + 4*q32;
            outp[(size_t)row*256] = f2b(us[rg]);
        }
    }
}

// ---- retrieve, row-split: 2 blocks/chunk (8 q-rows each), 256 blocks total ----
__global__ __launch_bounds__(512, 1) void kretr(const unsigned short* __restrict__ rnb,
        const unsigned short* __restrict__ WqTb, const unsigned short* __restrict__ WTb,
        const unsigned short* __restrict__ supb, const float* __restrict__ wpost,
        float* __restrict__ out){
    __shared__ unsigned short xs[8][XP];
    __shared__ float red[8][8];
    __shared__ float rs[8];
    int tid = threadIdx.x, w = tid >> 6, lane = tid & 63;
    int m16 = lane & 15, q16 = lane >> 4;
    int gb = blockIdx.x, g = gb >> 1, rh = gb & 1;
    int b = g >> 6, nl = g & 63;
    int rr = rh*8 + (m16 & 7);          // real source row (C rows 8..15 duplicate 0..7)

    {   // q projection
        s8v af[8];
        const unsigned short* arow = rnb + (size_t)g*4096 + rr*256 + q16*8;
        #pragma unroll
        for (int i = 0; i < 8; ++i) af[i] = *(const s8v*)(arow + i*32);
        #pragma unroll
        for (int t = 0; t < 2; ++t){
            int n0 = w*32 + t*16;
            f4v acc = {0.f,0.f,0.f,0.f};
            const unsigned short* br = WqTb + (size_t)(n0 + m16)*256 + q16*8;
            #pragma unroll
            for (int i = 0; i < 8; ++i){
                s8v bb = *(const s8v*)(br + i*32);
                acc = __builtin_amdgcn_mfma_f32_16x16x32_bf16(af[i], bb, acc, 0, 0, 0);
            }
            if (q16 < 2)
                #pragma unroll
                for (int r = 0; r < 4; ++r) xs[4*q16 + r][n0 + m16] = f2b(acc[r]);
        }
    }

    f4v facc[2];
    for (int l = 0; l < 4; ++l){
        __syncthreads();
        s8v xa[8];
        #pragma unroll
        for (int i = 0; i < 8; ++i)
            xa[i] = *(const s8v*)(&xs[m16 & 7][q16*8 + i*32]);
        __syncthreads();
        const unsigned short* Wt = WTb + (size_t)l*DDn;
        const unsigned short* Ut = supb + ((size_t)g*4 + l)*DDn;
        #pragma unroll
        for (int t = 0; t < 2; ++t){
            int n0 = w*32 + t*16;
            f4v acc = {0.f,0.f,0.f,0.f};
            const unsigned short* brW = Wt + (size_t)(n0 + m16)*256 + q16*8;
            const unsigned short* brU = Ut + (size_t)(n0 + m16)*256 + q16*8;
            #pragma unroll
            for (int i = 0; i < 8; ++i){
                s8v bW = *(const s8v*)(brW + i*32);
                s8v bU = *(const s8v*)(brU + i*32);
                acc = __builtin_amdgcn_mfma_f32_16x16x32_bf16(xa[i], bW, acc, 0, 0, 0);
                acc = __builtin_amdgcn_mfma_f32_16x16x32_bf16(xa[i], bU, acc, 0, 0, 0);
            }
            if (l < 3){
                if (q16 < 2)
                    #pragma unroll
                    for (int r = 0; r < 4; ++r)
                        xs[4*q16 + r][n0 + m16] = f2b(silu_(acc[r]));
            } else {
                facc[t] = acc;
            }
        }
    }

    // post rmsnorm over d for rows 0..7 (q16<2 lanes hold real rows)
    float part[4] = {0,0,0,0};
    #pragma unroll
    for (int t = 0; t < 2; ++t)
        #pragma unroll
        for (int r = 0; r < 4; ++r) part[r] += facc[t][r]*facc[t][r];
    #pragma unroll
    for (int off = 1; off < 16; off <<= 1)
        #pragma unroll
        for (int r = 0; r < 4; ++r) part[r] += __shfl_xor(part[r], off, 64);
    if (m16 == 0 && q16 < 2)
        #pragma unroll
        for (int r = 0; r < 4; ++r) red[w][4*q16 + r] = part[r];
    __syncthreads();
    if (tid < 8){
        float s = 0.f;
        #pragma unroll
        for (int ww = 0; ww < 8; ++ww) s += red[ww][tid];
        rs[tid] = rsqrtf(s*(1.f/256.f) + EPSf);
    }
    __syncthreads();
    if (q16 < 2){
        #pragma unroll
        for (int t = 0; t < 2; ++t){
            int d = w*32 + t*16 + m16;
            float wp = wpost[d];
            #pragma unroll
            for (int r = 0; r < 4; ++r){
                int c = 4*q16 + r;
                int tp = nl*16 + rh*8 + c + 15;
                if (tp < 1024)
                    out[((size_t)b*1024 + tp)*256 + d] = facc[t][r]*rs[c]*wp;
            }
        }
    }
    if (nl == 0 && rh == 0){
        for (int idx = tid; idx < 15*256; idx += 512)
            out[(size_t)b*262144 + idx] = 0.f;
    }
}

extern "C" void kernel_launch(void* const* d_in, const int* in_sizes, int n_in,
                              void* d_out, int out_size, void* d_ws, size_t ws_size,
                              hipStream_t stream) {
    const float* seq     = (const float*)d_in[0];
    const float* w_store = (const float*)d_in[1];
    const float* w_retr  = (const float*)d_in[2];
    const float* w_post  = (const float*)d_in[3];
    const float* Wq      = (const float*)d_in[4];
    const float* Wkv     = (const float*)d_in[5];
    const float* w_adapt = (const float*)d_in[6];
    const float* w_mom   = (const float*)d_in[7];
    const float* w_decay = (const float*)d_in[8];
    const float* W0      = (const float*)d_in[9];
    const float* W1      = (const float*)d_in[10];
    const float* W2      = (const float*)d_in[11];
    const float* W3      = (const float*)d_in[12];

    float* lrg   = (float*)d_ws;                  // 128
    float* momg  = lrg + NCn;                     // 128
    float* decg  = momg + NCn;                    // 128
    unsigned short* snb   = (unsigned short*)(decg + NCn + 32);
    unsigned short* rnb   = snb   + (size_t)NCn*4096;   // 524288 each
    unsigned short* WTb   = rnb   + (size_t)NCn*4096;   // 4*DDn
    unsigned short* Wb    = WTb   + 4*(size_t)DDn;      // 3*DDn
    unsigned short* WqTb  = Wb    + 3*(size_t)DDn;      // DDn
    unsigned short* WkvTb = WqTb  + (size_t)DDn;        // 2*DDn
    unsigned short* XT    = WkvTb + 2*(size_t)DDn;      // 2M
    unsigned short* GT    = XT    + (size_t)4*NCn*4096; // 2M
    unsigned short* supb  = GT    + (size_t)4*NCn*4096; // 33.5M (67MB)

    ktrans<<<dim3(8, 16, 6), 256, 0, stream>>>(Wq, Wkv, W0, W1, W2, W3,
                                               WTb, WqTb, WkvTb);
    kcopy <<<dim3(64, 1, 3), 256, 0, stream>>>(W1, W2, W3, Wb);
    knorm <<<dim3(2048),     256, 0, stream>>>(seq, w_store, w_retr, snb, rnb);
    kgates<<<dim3(NCn),      256, 0, stream>>>(snb, w_adapt, w_mom, w_decay,
                                               lrg, momg, decg);
    kfb   <<<dim3(2, NCn),   512, 0, stream>>>(snb, WkvTb, WTb, Wb, lrg, XT, GT);
    kupd  <<<dim3(64, 4, 2),  64, 0, stream>>>(XT, GT, momg, decg, supb);
    kretr <<<dim3(256),      512, 0, stream>>>(rnb, WqTb, WTb, supb, w_post,
                                               (float*)d_out);
}

// Round 6
// 195.560 us; speedup vs baseline: 2.5775x; 1.0130x over previous
//
#include <hip/hip_runtime.h>
#include <hip/hip_bf16.h>

typedef __attribute__((ext_vector_type(8)))  short s8v;   // 8 bf16 (4 VGPR)
typedef __attribute__((ext_vector_type(4)))  float f4v;   // 16x16 C/D
typedef __attribute__((ext_vector_type(16))) float f16v;  // 32x32 C/D

constexpr int Dd   = 256;
constexpr int Nn   = 64;
constexpr int NCn  = 128;
constexpr int DDn  = 65536;
constexpr int PPn  = 4 * DDn;
constexpr int XP   = 264;             // padded LDS row (bf16 elems)
constexpr float EPSf = 1.1920929e-07f;

__device__ __forceinline__ float sigm(float x){ return 1.0f/(1.0f + expf(-x)); }
__device__ __forceinline__ float silu_(float x){ return x * sigm(x); }
__device__ __forceinline__ float dsilu_(float x){ float s = sigm(x); return s*(1.0f + x*(1.0f - s)); }

__device__ __forceinline__ unsigned short f2b(float x){
    __hip_bfloat16 b = __float2bfloat16(x);
    unsigned short u; __builtin_memcpy(&u, &b, 2); return u;
}
__device__ __forceinline__ float b2f(unsigned short u){
    __hip_bfloat16 b; __builtin_memcpy(&b, &u, 2); return __bfloat162float(b);
}

__device__ __forceinline__ float block_sum(float v, float* red){
    #pragma unroll
    for (int off = 32; off; off >>= 1) v += __shfl_down(v, off, 64);
    if ((threadIdx.x & 63) == 0) red[threadIdx.x >> 6] = v;
    __syncthreads();
    float r = red[0] + red[1] + red[2] + red[3];
    __syncthreads();
    return r;
}

// ---- coalesced tiled transposes fp32 -> bf16 ----
__global__ __launch_bounds__(256) void ktrans(const float* __restrict__ Wq,
        const float* __restrict__ Wkv, const float* __restrict__ W0,
        const float* __restrict__ W1, const float* __restrict__ W2,
        const float* __restrict__ W3, unsigned short* __restrict__ WTb,
        unsigned short* __restrict__ WqTb, unsigned short* __restrict__ WkvTb){
    __shared__ float tl[32][33];
    int z = blockIdx.z;
    if (z != 5 && blockIdx.y >= 8) return;
    const float* S; unsigned short* T; int C;
    if (z < 4){ S = (z==0)?W0:(z==1)?W1:(z==2)?W2:W3; T = WTb + (size_t)z*DDn; C = 256; }
    else if (z == 4){ S = Wq; T = WqTb; C = 256; }
    else { S = Wkv; T = WkvTb; C = 512; }
    int k0 = blockIdx.x*32, j0 = blockIdx.y*32;
    int tx = threadIdx.x & 31, ty = threadIdx.x >> 5;
    #pragma unroll
    for (int p = 0; p < 4; ++p)
        tl[ty + 8*p][tx] = S[(size_t)(k0 + ty + 8*p)*C + j0 + tx];
    __syncthreads();
    #pragma unroll
    for (int p = 0; p < 4; ++p)
        T[(size_t)(j0 + ty + 8*p)*256 + k0 + tx] = f2b(tl[tx][ty + 8*p]);
}

// ---- vectorized cast-copy W1..W3 -> Wb ----
__global__ __launch_bounds__(256) void kcopy(const float* __restrict__ W1,
        const float* __restrict__ W2, const float* __restrict__ W3,
        unsigned short* __restrict__ Wb){
    int z = blockIdx.z;
    const float* S = (z==0)?W1:(z==1)?W2:W3;
    size_t idx = (size_t)blockIdx.x*1024 + threadIdx.x*4;
    float4 v = *(const float4*)(S + idx);
    ushort4 u; u.x = f2b(v.x); u.y = f2b(v.y); u.z = f2b(v.z); u.w = f2b(v.w);
    *(ushort4*)(Wb + (size_t)z*DDn + idx) = u;
}

// ---- per-token norm, scatter sn + shifted rn ----
__global__ __launch_bounds__(256) void knorm(const float* __restrict__ seq,
        const float* __restrict__ wsn, const float* __restrict__ wrn,
        unsigned short* __restrict__ snb, unsigned short* __restrict__ rnb){
    __shared__ float red[4];
    int t = blockIdx.x, d = threadIdx.x;
    int b = t >> 10, tl = t & 1023, g = t >> 4, c = tl & 15;
    float x = seq[(size_t)t*256 + d];
    float ss = block_sum(x*x, red);
    float xr = x * rsqrtf(ss*(1.f/256.f) + EPSf);
    snb[(size_t)g*4096 + c*256 + d] = f2b(xr*wsn[d]);
    if (tl >= 15){
        int tl2 = tl - 15, g2 = b*64 + (tl2 >> 4), c2 = tl2 & 15;
        rnb[(size_t)g2*4096 + c2*256 + d] = f2b(xr*wrn[d]);
    }
    if (tl >= 1009)
        rnb[(size_t)g*4096 + c*256 + d] = 0;
}

// ---- gates from bf16 sn chunk means ----
__global__ __launch_bounds__(256) void kgates(const unsigned short* __restrict__ snb,
        const float* __restrict__ wa, const float* __restrict__ wm,
        const float* __restrict__ wdk, float* __restrict__ lrg,
        float* __restrict__ momg, float* __restrict__ decg){
    __shared__ float red[4];
    int g = blockIdx.x, d = threadIdx.x;
    float a = 0.f;
    #pragma unroll
    for (int c = 0; c < 16; ++c) a += b2f(snb[(size_t)g*4096 + c*256 + d]);
    float cm = a * (1.f/16.f);
    float da = block_sum(cm*wa[d], red);
    float dm = block_sum(cm*wm[d], red);
    float dc = block_sum(cm*wdk[d], red);
    if (d == 0){ lrg[g] = sigm(da); momg[g] = sigm(dm); decg[g] = sigm(dc); }
}

// ---- fwd + bwd dgrads; writes transposed activations XT and grads GT ----
__global__ __launch_bounds__(512, 1) void kfb(const unsigned short* __restrict__ snb,
        const unsigned short* __restrict__ WkvTb, const unsigned short* __restrict__ WTb,
        const unsigned short* __restrict__ Wb, const float* __restrict__ lrg,
        unsigned short* __restrict__ XT, unsigned short* __restrict__ GT){
    __shared__ unsigned short xl[4][16][XP];
    __shared__ unsigned short Gs[16][XP];
    int tid = threadIdx.x, w = tid >> 6, lane = tid & 63;
    int m16 = lane & 15, q16 = lane >> 4;
    int g = blockIdx.y, bh = blockIdx.x;
    float sc = -2.f * lrg[g] * (1.f/256.f);

    s8v af[8];
    const unsigned short* arow = snb + (size_t)g*4096 + m16*256 + q16*8;
    #pragma unroll
    for (int i = 0; i < 8; ++i) af[i] = *(const s8v*)(arow + i*32);

    f4v vacc[2];
    #pragma unroll
    for (int t = 0; t < 2; ++t){
        int n0 = w*32 + t*16;
        f4v ka = {0.f,0.f,0.f,0.f}, va = {0.f,0.f,0.f,0.f};
        const unsigned short* brK = WkvTb + (size_t)(n0 + m16)*256 + q16*8;
        const unsigned short* brV = WkvTb + (size_t)(256 + n0 + m16)*256 + q16*8;
        #pragma unroll
        for (int i = 0; i < 8; ++i){
            s8v bK = *(const s8v*)(brK + i*32);
            s8v bV = *(const s8v*)(brV + i*32);
            ka = __builtin_amdgcn_mfma_f32_16x16x32_bf16(af[i], bK, ka, 0, 0, 0);
            va = __builtin_amdgcn_mfma_f32_16x16x32_bf16(af[i], bV, va, 0, 0, 0);
        }
        vacc[t] = va;
        #pragma unroll
        for (int r = 0; r < 4; ++r) xl[0][4*q16 + r][n0 + m16] = f2b(ka[r]);
    }

    f4v hreg[3][2];
    for (int l = 0; l < 3; ++l){
        __syncthreads();
        s8v xa[8];
        #pragma unroll
        for (int i = 0; i < 8; ++i)
            xa[i] = *(const s8v*)(&xl[l][m16][q16*8 + i*32]);
        const unsigned short* Wt = WTb + (size_t)l*DDn;
        #pragma unroll
        for (int t = 0; t < 2; ++t){
            int n0 = w*32 + t*16;
            f4v acc = {0.f,0.f,0.f,0.f};
            const unsigned short* br = Wt + (size_t)(n0 + m16)*256 + q16*8;
            #pragma unroll
            for (int i = 0; i < 8; ++i){
                s8v b = *(const s8v*)(br + i*32);
                acc = __builtin_amdgcn_mfma_f32_16x16x32_bf16(xa[i], b, acc, 0, 0, 0);
            }
            hreg[l][t] = acc;
            #pragma unroll
            for (int r = 0; r < 4; ++r)
                xl[l+1][4*q16 + r][n0 + m16] = f2b(silu_(acc[r]));
        }
    }
    __syncthreads();

    if (bh == 0){
        int d = tid & 255, half = tid >> 8;
        #pragma unroll
        for (int l = 0; l < 4; ++l){
            s8v v;
            #pragma unroll
            for (int j = 0; j < 8; ++j) v[j] = (short)xl[l][half*8 + j][d];
            *(s8v*)(XT + (((size_t)l*128 + g)*256 + d)*16 + half*8) = v;
        }
        return;
    }

    {   // layer 3 (pred) -> G4
        s8v xa[8];
        #pragma unroll
        for (int i = 0; i < 8; ++i)
            xa[i] = *(const s8v*)(&xl[3][m16][q16*8 + i*32]);
        const unsigned short* Wt = WTb + (size_t)3*DDn;
        #pragma unroll
        for (int t = 0; t < 2; ++t){
            int n0 = w*32 + t*16;
            f4v acc = {0.f,0.f,0.f,0.f};
            const unsigned short* br = Wt + (size_t)(n0 + m16)*256 + q16*8;
            #pragma unroll
            for (int i = 0; i < 8; ++i){
                s8v b = *(const s8v*)(br + i*32);
                acc = __builtin_amdgcn_mfma_f32_16x16x32_bf16(xa[i], b, acc, 0, 0, 0);
            }
            #pragma unroll
            for (int r = 0; r < 4; ++r)
                Gs[4*q16 + r][n0 + m16] = f2b(sc * (acc[r] - vacc[t][r]));
        }
    }
    __syncthreads();
    {
        int d = tid & 255, half = tid >> 8;
        s8v v;
        #pragma unroll
        for (int j = 0; j < 8; ++j) v[j] = (short)Gs[half*8 + j][d];
        *(s8v*)(GT + (((size_t)3*128 + g)*256 + d)*16 + half*8) = v;
    }

    for (int l = 3; l >= 1; --l){
        s8v gfa[8];
        #pragma unroll
        for (int i = 0; i < 8; ++i)
            gfa[i] = *(const s8v*)(&Gs[m16][q16*8 + i*32]);
        const unsigned short* Wr = Wb + (size_t)(l-1)*DDn;
        f4v gn[2];
        #pragma unroll
        for (int t = 0; t < 2; ++t){
            int n0 = w*32 + t*16;
            f4v acc = {0.f,0.f,0.f,0.f};
            const unsigned short* br = Wr + (size_t)(n0 + m16)*256 + q16*8;
            #pragma unroll
            for (int i = 0; i < 8; ++i){
                s8v b = *(const s8v*)(br + i*32);
                acc = __builtin_amdgcn_mfma_f32_16x16x32_bf16(gfa[i], b, acc, 0, 0, 0);
            }
            #pragma unroll
            for (int r = 0; r < 4; ++r)
                gn[t][r] = acc[r] * dsilu_(hreg[l-1][t][r]);
        }
        __syncthreads();
        #pragma unroll
        for (int t = 0; t < 2; ++t){
            int n0 = w*32 + t*16;
            #pragma unroll
            for (int r = 0; r < 4; ++r)
                Gs[4*q16 + r][n0 + m16] = f2b(gn[t][r]);
        }
        __syncthreads();
        {
            int d = tid & 255, half = tid >> 8;
            s8v v;
            #pragma unroll
            for (int j = 0; j < 8; ++j) v[j] = (short)Gs[half*8 + j][d];
            *(s8v*)(GT + (((size_t)(l-1)*128 + g)*256 + d)*16 + half*8) = v;
        }
    }
}

// ---- fused outer-product + scans -> updates (bf16), 1-deep load prefetch ----
__global__ __launch_bounds__(64, 1) void kupd(const unsigned short* __restrict__ XT,
        const unsigned short* __restrict__ GT, const float* __restrict__ momg,
        const float* __restrict__ decg, unsigned short* __restrict__ supb){
    int lane = threadIdx.x, m32 = lane & 31, q32 = lane >> 5;
    int tile = blockIdx.x, l = blockIdx.y, b = blockIdx.z;
    int r0 = (tile >> 3)*32, c0 = (tile & 7)*32;
    const unsigned short* gbase = GT + (size_t)l*128*4096 + (size_t)(r0 + m32)*16 + q32*8;
    const unsigned short* xbase = XT + (size_t)l*128*4096 + (size_t)(c0 + m32)*16 + q32*8;
    float ms[16], us[16];
    #pragma unroll
    for (int i = 0; i < 16; ++i){ ms[i] = 0.f; us[i] = 0.f; }
    s8v ga = *(const s8v*)(gbase + (size_t)(b*64)*4096);
    s8v xb = *(const s8v*)(xbase + (size_t)(b*64)*4096);
    for (int n = 0; n < 64; ++n){
        int gg = b*64 + n;
        s8v gan, xbn;
        if (n < 63){
            gan = *(const s8v*)(gbase + (size_t)(gg+1)*4096);
            xbn = *(const s8v*)(xbase + (size_t)(gg+1)*4096);
        }
        f16v z;
        #pragma unroll
        for (int i = 0; i < 16; ++i) z[i] = 0.f;
        f16v s = __builtin_amdgcn_mfma_f32_32x32x16_bf16(ga, xb, z, 0, 0, 0);
        float mo = momg[gg], de = 1.f - decg[gg];
        unsigned short* outp = supb + ((size_t)gg*4 + l)*DDn + c0 + m32;
        #pragma unroll
        for (int rg = 0; rg < 16; ++rg){
            ms[rg] = mo*ms[rg] + s[rg];
            us[rg] = de*us[rg] + ms[rg];
            int row = r0 + (rg & 3) + 8*(rg >> 2) + 4*q32;
            outp[(size_t)row*256] = f2b(us[rg]);
        }
        ga = gan; xb = xbn;
    }
}

// ---- one retrieval MLP layer, streaming, no barriers, no LDS ----
// mode 0: silu->bf16 Xout; 1: no act, fp32 Yout; 2: no act, bf16 Xout (q-proj)
__global__ __launch_bounds__(256, 1) void klayer(const unsigned short* __restrict__ Xin,
        const unsigned short* __restrict__ Wt, const unsigned short* __restrict__ supb,
        int l, unsigned short* __restrict__ Xout, float* __restrict__ Yout, int mode){
    int lane = threadIdx.x & 63, w = threadIdx.x >> 6;
    int m16 = lane & 15, q16 = lane >> 4;
    int g = blockIdx.y, n0 = blockIdx.x*64 + w*16;
    s8v a[8];
    const unsigned short* ar = Xin + (size_t)g*4096 + m16*256 + q16*8;
    #pragma unroll
    for (int i = 0; i < 8; ++i) a[i] = *(const s8v*)(ar + i*32);
    f4v acc = {0.f,0.f,0.f,0.f};
    const unsigned short* bw = Wt + (size_t)(n0 + m16)*256 + q16*8;
    #pragma unroll
    for (int i = 0; i < 8; ++i){
        s8v b = *(const s8v*)(bw + i*32);
        acc = __builtin_amdgcn_mfma_f32_16x16x32_bf16(a[i], b, acc, 0, 0, 0);
    }
    if (supb){
        const unsigned short* bu = supb + (size_t)l*DDn + (size_t)g*PPn
                                   + (size_t)(n0 + m16)*256 + q16*8;
        #pragma unroll
        for (int i = 0; i < 8; ++i){
            s8v b = *(const s8v*)(bu + i*32);
            acc = __builtin_amdgcn_mfma_f32_16x16x32_bf16(a[i], b, acc, 0, 0, 0);
        }
    }
    if (mode == 1){
        #pragma unroll
        for (int r = 0; r < 4; ++r)
            Yout[((size_t)g*16 + 4*q16 + r)*256 + n0 + m16] = acc[r];
    } else {
        #pragma unroll
        for (int r = 0; r < 4; ++r){
            float v = (mode == 0) ? silu_(acc[r]) : acc[r];
            Xout[(size_t)g*4096 + (4*q16 + r)*256 + n0 + m16] = f2b(v);
        }
    }
}

// ---- post rmsnorm + output shift (2048 blocks) ----
__global__ __launch_bounds__(256) void knormout(const float* __restrict__ y3,
        const float* __restrict__ wpost, float* __restrict__ out){
    __shared__ float red[4];
    int tt = blockIdx.x, d = threadIdx.x;
    int g = tt >> 4, c = tt & 15, b = g >> 6, n = g & 63;
    float y = y3[(size_t)tt*256 + d];
    float ss = block_sum(y*y, red);
    float val = y * rsqrtf(ss*(1.f/256.f) + EPSf) * wpost[d];
    int tp = n*16 + c + 15;
    if (tp < 1024) out[((size_t)b*1024 + tp)*256 + d] = val;
    if (n == 0 && c == 0){
        #pragma unroll
        for (int t2 = 0; t2 < 15; ++t2) out[((size_t)b*1024 + t2)*256 + d] = 0.f;
    }
}

extern "C" void kernel_launch(void* const* d_in, const int* in_sizes, int n_in,
                              void* d_out, int out_size, void* d_ws, size_t ws_size,
                              hipStream_t stream) {
    const float* seq     = (const float*)d_in[0];
    const float* w_store = (const float*)d_in[1];
    const float* w_retr  = (const float*)d_in[2];
    const float* w_post  = (const float*)d_in[3];
    const float* Wq      = (const float*)d_in[4];
    const float* Wkv     = (const float*)d_in[5];
    const float* w_adapt = (const float*)d_in[6];
    const float* w_mom   = (const float*)d_in[7];
    const float* w_decay = (const float*)d_in[8];
    const float* W0      = (const float*)d_in[9];
    const float* W1      = (const float*)d_in[10];
    const float* W2      = (const float*)d_in[11];
    const float* W3      = (const float*)d_in[12];

    float* lrg   = (float*)d_ws;                  // 128
    float* momg  = lrg + NCn;                     // 128
    float* decg  = momg + NCn;                    // 128
    unsigned short* snb   = (unsigned short*)(decg + NCn + 32);
    unsigned short* rnb   = snb   + (size_t)NCn*4096;
    unsigned short* WTb   = rnb   + (size_t)NCn*4096;
    unsigned short* Wb    = WTb   + 4*(size_t)DDn;
    unsigned short* WqTb  = Wb    + 3*(size_t)DDn;
    unsigned short* WkvTb = WqTb  + (size_t)DDn;
    unsigned short* XT    = WkvTb + 2*(size_t)DDn;      // 2M ushorts
    unsigned short* GT    = XT    + (size_t)4*NCn*4096; // 2M ushorts
    unsigned short* supb  = GT    + (size_t)4*NCn*4096; // 33.5M (67MB)
    // retrieval reuse (dead after kupd): x ping-pong in XT, y3 in GT
    unsigned short* xr0 = XT;
    unsigned short* xr1 = XT + (size_t)NCn*4096;
    float* y3 = (float*)GT;                             // 2MB of GT's 4MB

    ktrans<<<dim3(8, 16, 6), 256, 0, stream>>>(Wq, Wkv, W0, W1, W2, W3,
                                               WTb, WqTb, WkvTb);
    kcopy <<<dim3(64, 1, 3), 256, 0, stream>>>(W1, W2, W3, Wb);
    knorm <<<dim3(2048),     256, 0, stream>>>(seq, w_store, w_retr, snb, rnb);
    kgates<<<dim3(NCn),      256, 0, stream>>>(snb, w_adapt, w_mom, w_decay,
                                               lrg, momg, decg);
    kfb   <<<dim3(2, NCn),   512, 0, stream>>>(snb, WkvTb, WTb, Wb, lrg, XT, GT);
    kupd  <<<dim3(64, 4, 2),  64, 0, stream>>>(XT, GT, momg, decg, supb);
    // retrieval: q-proj + 4 fast-weight layers + post-norm
    klayer<<<dim3(4, NCn), 256, 0, stream>>>(rnb, WqTb, nullptr, 0, xr0, nullptr, 2);
    klayer<<<dim3(4, NCn), 256, 0, stream>>>(xr0, WTb + 0*(size_t)DDn, supb, 0, xr1, nullptr, 0);
    klayer<<<dim3(4, NCn), 256, 0, stream>>>(xr1, WTb + 1*(size_t)DDn, supb, 1, xr0, nullptr, 0);
    klayer<<<dim3(4, NCn), 256, 0, stream>>>(xr0, WTb + 2*(size_t)DDn, supb, 2, xr1, nullptr, 0);
    klayer<<<dim3(4, NCn), 256, 0, stream>>>(xr1, WTb + 3*(size_t)DDn, supb, 3, nullptr, y3, 1);
    knormout<<<dim3(2048), 256, 0, stream>>>(y3, w_post, (float*)d_out);
}

// Round 7
// 191.493 us; speedup vs baseline: 2.6322x; 1.0212x over previous
//
#include <hip/hip_runtime.h>
#include <hip/hip_bf16.h>

typedef __attribute__((ext_vector_type(8)))  short s8v;   // 8 bf16
typedef __attribute__((ext_vector_type(4)))  float f4v;   // 16x16 C/D
typedef _Float16 h4 __attribute__((ext_vector_type(4)));  // 4 f16

constexpr int Dd   = 256;
constexpr int Nn   = 64;
constexpr int NCn  = 128;
constexpr int DDn  = 65536;
constexpr int PPn  = 4 * DDn;
constexpr int XP   = 264;             // padded LDS row (bf16 elems)
constexpr float EPSf = 1.1920929e-07f;

__device__ __forceinline__ float sigm(float x){ return 1.0f/(1.0f + expf(-x)); }
__device__ __forceinline__ float silu_(float x){ return x * sigm(x); }
__device__ __forceinline__ float dsilu_(float x){ float s = sigm(x); return s*(1.0f + x*(1.0f - s)); }

__device__ __forceinline__ unsigned short f2b(float x){
    __hip_bfloat16 b = __float2bfloat16(x);
    unsigned short u; __builtin_memcpy(&u, &b, 2); return u;
}
__device__ __forceinline__ float b2f(unsigned short u){
    __hip_bfloat16 b; __builtin_memcpy(&b, &u, 2); return __bfloat162float(b);
}
__device__ __forceinline__ unsigned short f2hu(float x){
    _Float16 h = (_Float16)x;
    unsigned short u; __builtin_memcpy(&u, &h, 2); return u;
}
__device__ __forceinline__ h4 ldh4(const unsigned short* p){
    h4 r; __builtin_memcpy(&r, p, 8); return r;
}

__device__ __forceinline__ float block_sum(float v, float* red){   // 256 thr
    #pragma unroll
    for (int off = 32; off; off >>= 1) v += __shfl_down(v, off, 64);
    if ((threadIdx.x & 63) == 0) red[threadIdx.x >> 6] = v;
    __syncthreads();
    float r = red[0] + red[1] + red[2] + red[3];
    __syncthreads();
    return r;
}
__device__ __forceinline__ float block_sum8(float v, float* red){  // 512 thr
    #pragma unroll
    for (int off = 32; off; off >>= 1) v += __shfl_down(v, off, 64);
    if ((threadIdx.x & 63) == 0) red[threadIdx.x >> 6] = v;
    __syncthreads();
    float r = 0.f;
    #pragma unroll
    for (int i = 0; i < 8; ++i) r += red[i];
    __syncthreads();
    return r;
}

// ---- merged weight prep: z 0..5 tiled transpose fp32->bf16, z 6..8 cast-copy ----
__global__ __launch_bounds__(256) void ktw(const float* __restrict__ Wq,
        const float* __restrict__ Wkv, const float* __restrict__ W0,
        const float* __restrict__ W1, const float* __restrict__ W2,
        const float* __restrict__ W3, unsigned short* __restrict__ WTb,
        unsigned short* __restrict__ WqTb, unsigned short* __restrict__ WkvTb,
        unsigned short* __restrict__ Wb){
    int z = blockIdx.z;
    if (z >= 6){
        const float* S = (z==6)?W1:(z==7)?W2:W3;
        size_t idx = (((size_t)blockIdx.y*8 + blockIdx.x)*256 + threadIdx.x)*2;
        float2 v = *(const float2*)(S + idx);
        ushort2 u; u.x = f2b(v.x); u.y = f2b(v.y);
        *(ushort2*)(Wb + (size_t)(z-6)*DDn + idx) = u;
        return;
    }
    __shared__ float tl[32][33];
    if (z != 5 && blockIdx.y >= 8) return;
    const float* S; unsigned short* T; int C;
    if (z < 4){ S = (z==0)?W0:(z==1)?W1:(z==2)?W2:W3; T = WTb + (size_t)z*DDn; C = 256; }
    else if (z == 4){ S = Wq; T = WqTb; C = 256; }
    else { S = Wkv; T = WkvTb; C = 512; }
    int k0 = blockIdx.x*32, j0 = blockIdx.y*32;
    int tx = threadIdx.x & 31, ty = threadIdx.x >> 5;
    #pragma unroll
    for (int p = 0; p < 4; ++p)
        tl[ty + 8*p][tx] = S[(size_t)(k0 + ty + 8*p)*C + j0 + tx];
    __syncthreads();
    #pragma unroll
    for (int p = 0; p < 4; ++p)
        T[(size_t)(j0 + ty + 8*p)*256 + k0 + tx] = f2b(tl[tx][ty + 8*p]);
}

// ---- per-token norm, scatter sn + shifted rn ----
__global__ __launch_bounds__(256) void knorm(const float* __restrict__ seq,
        const float* __restrict__ wsn, const float* __restrict__ wrn,
        unsigned short* __restrict__ snb, unsigned short* __restrict__ rnb){
    __shared__ float red[4];
    int t = blockIdx.x, d = threadIdx.x;
    int b = t >> 10, tl = t & 1023, g = t >> 4, c = tl & 15;
    float x = seq[(size_t)t*256 + d];
    float ss = block_sum(x*x, red);
    float xr = x * rsqrtf(ss*(1.f/256.f) + EPSf);
    snb[(size_t)g*4096 + c*256 + d] = f2b(xr*wsn[d]);
    if (tl >= 15){
        int tl2 = tl - 15, g2 = b*64 + (tl2 >> 4), c2 = tl2 & 15;
        rnb[(size_t)g2*4096 + c2*256 + d] = f2b(xr*wrn[d]);
    }
    if (tl >= 1009)
        rnb[(size_t)g*4096 + c*256 + d] = 0;
}

// ---- fwd + bwd dgrads + fused gates; writes f16 XT (bh=0) and f16 GT (bh=1) ----
__global__ __launch_bounds__(512, 1) void kfb(const unsigned short* __restrict__ snb,
        const unsigned short* __restrict__ WkvTb, const unsigned short* __restrict__ WTb,
        const unsigned short* __restrict__ Wb,
        const float* __restrict__ wa, const float* __restrict__ wm,
        const float* __restrict__ wdk,
        float* __restrict__ momg, float* __restrict__ decg,
        unsigned short* __restrict__ XT, unsigned short* __restrict__ GT){
    __shared__ unsigned short xl[4][16][XP];
    __shared__ unsigned short Gs[16][XP];
    __shared__ float red8[8];
    int tid = threadIdx.x, w = tid >> 6, lane = tid & 63;
    int m16 = lane & 15, q16 = lane >> 4;
    int g = blockIdx.y, bh = blockIdx.x;

    float sc = 0.f;
    if (bh == 1){   // fused gates (block-uniform branch)
        int d2 = tid & 255, hf = tid >> 8;
        float a = 0.f;
        #pragma unroll
        for (int c = 0; c < 8; ++c)
            a += b2f(snb[(size_t)g*4096 + (hf*8 + c)*256 + d2]);
        float cm = a * (1.f/16.f);
        float da = block_sum8(cm*wa[d2],  red8);
        float dm = block_sum8(cm*wm[d2],  red8);
        float dc = block_sum8(cm*wdk[d2], red8);
        sc = -2.f * sigm(da) * (1.f/256.f);
        if (tid == 0){ momg[g] = sigm(dm); decg[g] = sigm(dc); }
    }

    s8v af[8];
    const unsigned short* arow = snb + (size_t)g*4096 + m16*256 + q16*8;
    #pragma unroll
    for (int i = 0; i < 8; ++i) af[i] = *(const s8v*)(arow + i*32);

    f4v vacc[2];
    #pragma unroll
    for (int t = 0; t < 2; ++t){
        int n0 = w*32 + t*16;
        f4v ka = {0.f,0.f,0.f,0.f}, va = {0.f,0.f,0.f,0.f};
        const unsigned short* brK = WkvTb + (size_t)(n0 + m16)*256 + q16*8;
        const unsigned short* brV = WkvTb + (size_t)(256 + n0 + m16)*256 + q16*8;
        #pragma unroll
        for (int i = 0; i < 8; ++i){
            s8v bK = *(const s8v*)(brK + i*32);
            s8v bV = *(const s8v*)(brV + i*32);
            ka = __builtin_amdgcn_mfma_f32_16x16x32_bf16(af[i], bK, ka, 0, 0, 0);
            va = __builtin_amdgcn_mfma_f32_16x16x32_bf16(af[i], bV, va, 0, 0, 0);
        }
        vacc[t] = va;
        #pragma unroll
        for (int r = 0; r < 4; ++r) xl[0][4*q16 + r][n0 + m16] = f2b(ka[r]);
    }

    f4v hreg[3][2];
    for (int l = 0; l < 3; ++l){
        __syncthreads();
        s8v xa[8];
        #pragma unroll
        for (int i = 0; i < 8; ++i)
            xa[i] = *(const s8v*)(&xl[l][m16][q16*8 + i*32]);
        const unsigned short* Wt = WTb + (size_t)l*DDn;
        #pragma unroll
        for (int t = 0; t < 2; ++t){
            int n0 = w*32 + t*16;
            f4v acc = {0.f,0.f,0.f,0.f};
            const unsigned short* br = Wt + (size_t)(n0 + m16)*256 + q16*8;
            #pragma unroll
            for (int i = 0; i < 8; ++i){
                s8v b = *(const s8v*)(br + i*32);
                acc = __builtin_amdgcn_mfma_f32_16x16x32_bf16(xa[i], b, acc, 0, 0, 0);
            }
            hreg[l][t] = acc;
            #pragma unroll
            for (int r = 0; r < 4; ++r)
                xl[l+1][4*q16 + r][n0 + m16] = f2b(silu_(acc[r]));
        }
    }
    __syncthreads();

    if (bh == 0){   // write f16 transposed activations XT[l][g][d][c]
        int d = tid & 255, half = tid >> 8;
        #pragma unroll
        for (int l = 0; l < 4; ++l){
            s8v v;
            #pragma unroll
            for (int j = 0; j < 8; ++j)
                v[j] = (short)f2hu(b2f(xl[l][half*8 + j][d]));
            *(s8v*)(XT + (((size_t)l*128 + g)*256 + d)*16 + half*8) = v;
        }
        return;
    }

    {   // layer 3 (pred) -> G4
        s8v xa[8];
        #pragma unroll
        for (int i = 0; i < 8; ++i)
            xa[i] = *(const s8v*)(&xl[3][m16][q16*8 + i*32]);
        const unsigned short* Wt = WTb + (size_t)3*DDn;
        #pragma unroll
        for (int t = 0; t < 2; ++t){
            int n0 = w*32 + t*16;
            f4v acc = {0.f,0.f,0.f,0.f};
            const unsigned short* br = Wt + (size_t)(n0 + m16)*256 + q16*8;
            #pragma unroll
            for (int i = 0; i < 8; ++i){
                s8v b = *(const s8v*)(br + i*32);
                acc = __builtin_amdgcn_mfma_f32_16x16x32_bf16(xa[i], b, acc, 0, 0, 0);
            }
            #pragma unroll
            for (int r = 0; r < 4; ++r)
                Gs[4*q16 + r][n0 + m16] = f2b(sc * (acc[r] - vacc[t][r]));
        }
    }
    __syncthreads();
    {   // write f16 GT[3]
        int d = tid & 255, half = tid >> 8;
        s8v v;
        #pragma unroll
        for (int j = 0; j < 8; ++j)
            v[j] = (short)f2hu(b2f(Gs[half*8 + j][d]));
        *(s8v*)(GT + (((size_t)3*128 + g)*256 + d)*16 + half*8) = v;
    }

    for (int l = 3; l >= 1; --l){
        s8v gfa[8];
        #pragma unroll
        for (int i = 0; i < 8; ++i)
            gfa[i] = *(const s8v*)(&Gs[m16][q16*8 + i*32]);
        const unsigned short* Wr = Wb + (size_t)(l-1)*DDn;
        f4v gn[2];
        #pragma unroll
        for (int t = 0; t < 2; ++t){
            int n0 = w*32 + t*16;
            f4v acc = {0.f,0.f,0.f,0.f};
            const unsigned short* br = Wr + (size_t)(n0 + m16)*256 + q16*8;
            #pragma unroll
            for (int i = 0; i < 8; ++i){
                s8v b = *(const s8v*)(br + i*32);
                acc = __builtin_amdgcn_mfma_f32_16x16x32_bf16(gfa[i], b, acc, 0, 0, 0);
            }
            #pragma unroll
            for (int r = 0; r < 4; ++r)
                gn[t][r] = acc[r] * dsilu_(hreg[l-1][t][r]);
        }
        __syncthreads();
        #pragma unroll
        for (int t = 0; t < 2; ++t){
            int n0 = w*32 + t*16;
            #pragma unroll
            for (int r = 0; r < 4; ++r)
                Gs[4*q16 + r][n0 + m16] = f2b(gn[t][r]);
        }
        __syncthreads();
        {
            int d = tid & 255, half = tid >> 8;
            s8v v;
            #pragma unroll
            for (int j = 0; j < 8; ++j)
                v[j] = (short)f2hu(b2f(Gs[half*8 + j][d]));
            *(s8v*)(GT + (((size_t)(l-1)*128 + g)*256 + d)*16 + half*8) = v;
        }
    }
}

// ---- fused outer-product + scans -> updates (bf16), 16x16 f16 MFMA tiles ----
// grid (16 rtiles, 16 ctiles, 8 = l + 4*b), 64 threads (1 wave)
__global__ __launch_bounds__(64, 1) void kupd(const unsigned short* __restrict__ XT,
        const unsigned short* __restrict__ GT, const float* __restrict__ momg,
        const float* __restrict__ decg, unsigned short* __restrict__ supb){
    int lane = threadIdx.x, m16 = lane & 15, q16 = lane >> 4;
    int l = blockIdx.z & 3, b = blockIdx.z >> 2;
    int r0 = blockIdx.x*16, c0 = blockIdx.y*16;
    const unsigned short* gbase = GT + (((size_t)l*128 + b*64)*256 + r0 + m16)*16 + q16*4;
    const unsigned short* xbase = XT + (((size_t)l*128 + b*64)*256 + c0 + m16)*16 + q16*4;
    float ms[4] = {0,0,0,0}, us[4] = {0,0,0,0};
    h4 ga = ldh4(gbase);
    h4 xv = ldh4(xbase);
    for (int n = 0; n < 64; ++n){
        int gg = b*64 + n;
        h4 gan, xvn;
        if (n < 63){
            gan = ldh4(gbase + (size_t)(n+1)*4096);
            xvn = ldh4(xbase + (size_t)(n+1)*4096);
        }
        f4v z = {0.f,0.f,0.f,0.f};
        f4v s = __builtin_amdgcn_mfma_f32_16x16x16f16(ga, xv, z, 0, 0, 0);
        float mo = momg[gg], de = 1.f - decg[gg];
        unsigned short* outp = supb + ((size_t)gg*4 + l)*DDn + c0 + m16;
        #pragma unroll
        for (int r = 0; r < 4; ++r){
            ms[r] = mo*ms[r] + s[r];
            us[r] = de*us[r] + ms[r];
            int row = r0 + q16*4 + r;
            outp[(size_t)row*256] = f2b(us[r]);
        }
        ga = gan; xv = xvn;
    }
}

// ---- one retrieval MLP layer, streaming, no barriers, no LDS ----
// mode 0: silu->bf16 Xout; 2: no act, bf16 Xout (q-proj)
__global__ __launch_bounds__(256, 1) void klayer(const unsigned short* __restrict__ Xin,
        const unsigned short* __restrict__ Wt, const unsigned short* __restrict__ supb,
        int l, unsigned short* __restrict__ Xout, int mode){
    int lane = threadIdx.x & 63, w = threadIdx.x >> 6;
    int m16 = lane & 15, q16 = lane >> 4;
    int g = blockIdx.y, n0 = blockIdx.x*64 + w*16;
    s8v a[8];
    const unsigned short* ar = Xin + (size_t)g*4096 + m16*256 + q16*8;
    #pragma unroll
    for (int i = 0; i < 8; ++i) a[i] = *(const s8v*)(ar + i*32);
    f4v acc = {0.f,0.f,0.f,0.f};
    const unsigned short* bw = Wt + (size_t)(n0 + m16)*256 + q16*8;
    #pragma unroll
    for (int i = 0; i < 8; ++i){
        s8v b = *(const s8v*)(bw + i*32);
        acc = __builtin_amdgcn_mfma_f32_16x16x32_bf16(a[i], b, acc, 0, 0, 0);
    }
    if (supb){
        const unsigned short* bu = supb + (size_t)l*DDn + (size_t)g*PPn
                                   + (size_t)(n0 + m16)*256 + q16*8;
        #pragma unroll
        for (int i = 0; i < 8; ++i){
            s8v b = *(const s8v*)(bu + i*32);
            acc = __builtin_amdgcn_mfma_f32_16x16x32_bf16(a[i], b, acc, 0, 0, 0);
        }
    }
    #pragma unroll
    for (int r = 0; r < 4; ++r){
        float v = (mode == 0) ? silu_(acc[r]) : acc[r];
        Xout[(size_t)g*4096 + (4*q16 + r)*256 + n0 + m16] = f2b(v);
    }
}

// ---- final fast-weight layer + post rmsnorm + shift + zero rows, fused ----
// grid (NCn), 256 thr: wave w owns cols w*64..w*64+63
__global__ __launch_bounds__(256, 1) void klast(const unsigned short* __restrict__ Xin,
        const unsigned short* __restrict__ Wt, const unsigned short* __restrict__ supb,
        const float* __restrict__ wpost, float* __restrict__ out){
    __shared__ float red[4][16];
    __shared__ float rs[16];
    int tid = threadIdx.x, w = tid >> 6, lane = tid & 63;
    int m16 = lane & 15, q16 = lane >> 4;
    int g = blockIdx.x, b = g >> 6, nl = g & 63;
    s8v a[8];
    const unsigned short* ar = Xin + (size_t)g*4096 + m16*256 + q16*8;
    #pragma unroll
    for (int i = 0; i < 8; ++i) a[i] = *(const s8v*)(ar + i*32);
    f4v acc[4];
    #pragma unroll
    for (int t = 0; t < 4; ++t){
        int n0 = w*64 + t*16;
        f4v ac = {0.f,0.f,0.f,0.f};
        const unsigned short* bw = Wt + (size_t)(n0 + m16)*256 + q16*8;
        const unsigned short* bu = supb + (size_t)3*DDn + (size_t)g*PPn
                                   + (size_t)(n0 + m16)*256 + q16*8;
        #pragma unroll
        for (int i = 0; i < 8; ++i){
            s8v bW = *(const s8v*)(bw + i*32);
            s8v bU = *(const s8v*)(bu + i*32);
            ac = __builtin_amdgcn_mfma_f32_16x16x32_bf16(a[i], bW, ac, 0, 0, 0);
            ac = __builtin_amdgcn_mfma_f32_16x16x32_bf16(a[i], bU, ac, 0, 0, 0);
        }
        acc[t] = ac;
    }
    // row sums of squares (rows c = 4*q16+r, cols across 4 waves)
    float part[4] = {0,0,0,0};
    #pragma unroll
    for (int t = 0; t < 4; ++t)
        #pragma unroll
        for (int r = 0; r < 4; ++r) part[r] += acc[t][r]*acc[t][r];
    #pragma unroll
    for (int off = 1; off < 16; off <<= 1)
        #pragma unroll
        for (int r = 0; r < 4; ++r) part[r] += __shfl_xor(part[r], off, 64);
    if (m16 == 0)
        #pragma unroll
        for (int r = 0; r < 4; ++r) red[w][4*q16 + r] = part[r];
    __syncthreads();
    if (tid < 16){
        float s = red[0][tid] + red[1][tid] + red[2][tid] + red[3][tid];
        rs[tid] = rsqrtf(s*(1.f/256.f) + EPSf);
    }
    __syncthreads();
    #pragma unroll
    for (int t = 0; t < 4; ++t){
        int d = w*64 + t*16 + m16;
        float wp = wpost[d];
        #pragma unroll
        for (int r = 0; r < 4; ++r){
            int c = 4*q16 + r;
            int tp = nl*16 + c + 15;
            if (tp < 1024)
                out[((size_t)b*1024 + tp)*256 + d] = acc[t][r]*rs[c]*wp;
        }
    }
    if (nl == 0){
        for (int idx = tid; idx < 15*256; idx += 256)
            out[(size_t)b*262144 + idx] = 0.f;
    }
}

extern "C" void kernel_launch(void* const* d_in, const int* in_sizes, int n_in,
                              void* d_out, int out_size, void* d_ws, size_t ws_size,
                              hipStream_t stream) {
    const float* seq     = (const float*)d_in[0];
    const float* w_store = (const float*)d_in[1];
    const float* w_retr  = (const float*)d_in[2];
    const float* w_post  = (const float*)d_in[3];
    const float* Wq      = (const float*)d_in[4];
    const float* Wkv     = (const float*)d_in[5];
    const float* w_adapt = (const float*)d_in[6];
    const float* w_mom   = (const float*)d_in[7];
    const float* w_decay = (const float*)d_in[8];
    const float* W0      = (const float*)d_in[9];
    const float* W1      = (const float*)d_in[10];
    const float* W2      = (const float*)d_in[11];
    const float* W3      = (const float*)d_in[12];

    float* momg  = (float*)d_ws;                  // 128
    float* decg  = momg + NCn;                    // 128
    unsigned short* snb   = (unsigned short*)(decg + NCn + 32);
    unsigned short* rnb   = snb   + (size_t)NCn*4096;
    unsigned short* WTb   = rnb   + (size_t)NCn*4096;
    unsigned short* Wb    = WTb   + 4*(size_t)DDn;
    unsigned short* WqTb  = Wb    + 3*(size_t)DDn;
    unsigned short* WkvTb = WqTb  + (size_t)DDn;
    unsigned short* XT    = WkvTb + 2*(size_t)DDn;      // 2M ushorts (f16)
    unsigned short* GT    = XT    + (size_t)4*NCn*4096; // 2M ushorts (f16)
    unsigned short* supb  = GT    + (size_t)4*NCn*4096; // 33.5M (67MB, bf16)
    // retrieval x ping-pong reuses XT region (dead after kupd)
    unsigned short* xr0 = XT;
    unsigned short* xr1 = XT + (size_t)NCn*4096;

    ktw   <<<dim3(8, 16, 9), 256, 0, stream>>>(Wq, Wkv, W0, W1, W2, W3,
                                               WTb, WqTb, WkvTb, Wb);
    knorm <<<dim3(2048),     256, 0, stream>>>(seq, w_store, w_retr, snb, rnb);
    kfb   <<<dim3(2, NCn),   512, 0, stream>>>(snb, WkvTb, WTb, Wb,
                                               w_adapt, w_mom, w_decay,
                                               momg, decg, XT, GT);
    kupd  <<<dim3(16, 16, 8), 64, 0, stream>>>(XT, GT, momg, decg, supb);
    // retrieval: q-proj + 3 fast-weight layers + fused last layer/norm/shift
    klayer<<<dim3(4, NCn), 256, 0, stream>>>(rnb, WqTb, nullptr, 0, xr0, 2);
    klayer<<<dim3(4, NCn), 256, 0, stream>>>(xr0, WTb + 0*(size_t)DDn, supb, 0, xr1, 0);
    klayer<<<dim3(4, NCn), 256, 0, stream>>>(xr1, WTb + 1*(size_t)DDn, supb, 1, xr0, 0);
    klayer<<<dim3(4, NCn), 256, 0, stream>>>(xr0, WTb + 2*(size_t)DDn, supb, 2, xr1, 0);
    klast <<<dim3(NCn),    256, 0, stream>>>(xr1, WTb + 3*(size_t)DDn, supb,
                                             w_post, (float*)d_out);
}